// Round 12
// baseline (163.952 us; speedup 1.0000x reference)
//
#include <hip/hip_runtime.h>
#include <stdint.h>

typedef unsigned short u16;
typedef __attribute__((ext_vector_type(8))) short bf16x8;
typedef __attribute__((ext_vector_type(4))) float f32x4;
typedef __attribute__((ext_vector_type(4))) unsigned short u16x4;
typedef __attribute__((ext_vector_type(4))) unsigned int u32x4;

#define DEVI static __device__ __forceinline__

// dots*scale folded into Q, with base-2 softmax: exp(s) == exp2(s*log2e)
#define QSCALE (0.125f * 1.4426950408889634f)

DEVI u16 f2bf(float f) {
  union { float f; unsigned int u; } v; v.f = f;
  unsigned int u = v.u + 0x7fffu + ((v.u >> 16) & 1u);
  return (u16)(u >> 16);
}
DEVI void gl16(const void* g, void* l) {
  __builtin_amdgcn_global_load_lds(
      (__attribute__((address_space(1))) void*)g,
      (__attribute__((address_space(3))) void*)l, 16, 0, 0);
}
// packed f32x2 -> bf16x2 (RNE), lo=bf16(a), hi=bf16(b)
DEVI unsigned int cvtpk(float a, float b) {
  unsigned int r;
  asm("v_cvt_pk_bf16_f32 %0, %1, %2" : "=v"(r) : "v"(a), "v"(b));
  return r;
}
// raw v_exp_f32 (flushes f32 denormal results -- fine: such P vanish in the
// bf16 P / fp32 sum anyway). s_nop 0 covers the trans->use wait state.
DEVI float fexp2(float x) {
  float r;
  asm("v_exp_f32 %0, %1\n\ts_nop 0" : "=v"(r) : "v"(x));
  return r;
}
DEVI float fmax4(f32x4 v) {
  return fmaxf(fmaxf(v[0], v[1]), fmaxf(v[2], v[3]));
}

// ---------------- K1: LayerNorm -> bf16 ----------------
__global__ __launch_bounds__(256) void k_ln_split(
    const float* __restrict__ x, const float* __restrict__ gamma,
    const float* __restrict__ beta, u16* __restrict__ xh) {
  const int row = blockIdx.x;          // 8192 rows
  const int t = threadIdx.x;           // 256 threads, 4 floats each
  const float4* xr = (const float4*)(x + (size_t)row * 1024);
  float4 v = xr[t];
  float s = v.x + v.y + v.z + v.w;
  float s2 = v.x * v.x + v.y * v.y + v.z * v.z + v.w * v.w;
  #pragma unroll
  for (int m = 1; m < 64; m <<= 1) { s += __shfl_xor(s, m); s2 += __shfl_xor(s2, m); }
  __shared__ float ls[4], ls2[4];
  if ((t & 63) == 0) { ls[t >> 6] = s; ls2[t >> 6] = s2; }
  __syncthreads();
  s = ls[0] + ls[1] + ls[2] + ls[3];
  s2 = ls2[0] + ls2[1] + ls2[2] + ls2[3];
  float mu = s * (1.0f / 1024.0f);
  float var = s2 * (1.0f / 1024.0f) - mu * mu;
  float rstd = rsqrtf(var + 1e-5f);
  float4 g = ((const float4*)gamma)[t];
  float4 b = ((const float4*)beta)[t];
  float xv[4] = {v.x, v.y, v.z, v.w};
  float gg[4] = {g.x, g.y, g.z, g.w};
  float bb[4] = {b.x, b.y, b.z, b.w};
  u16x4 hv;
  #pragma unroll
  for (int i = 0; i < 4; i++) {
    float xn = (xv[i] - mu) * rstd * gg[i] + bb[i];
    hv[i] = f2bf(xn);
  }
  ((u16x4*)xh)[(size_t)row * 256 + t] = hv;
}

// ---------------- K1b: transpose weights, fp32 -> bf16 ----------------
__global__ __launch_bounds__(256) void k_wsplit_t(
    const float* __restrict__ W, u16* __restrict__ Wth, int K, int N) {
  __shared__ float tile[32][33];
  const int t = threadIdx.x;
  const int tx = t & 31, ty = t >> 5;  // ty in 0..7
  #pragma unroll
  for (int i = 0; i < 4; i++) {
    int k = blockIdx.y * 32 + ty + i * 8;
    int n = blockIdx.x * 32 + tx;
    tile[ty + i * 8][tx] = W[(size_t)k * N + n];
  }
  __syncthreads();
  #pragma unroll
  for (int i = 0; i < 4; i++) {
    int n = blockIdx.x * 32 + ty + i * 8;   // output row
    int k = blockIdx.y * 32 + tx;           // output col
    Wth[(size_t)n * K + k] = f2bf(tile[tx][ty + i * 8]);
  }
}

// ---------------- K2/K4: bf16 GEMM, BK=64, XOR-swizzled, 2-phase dbuf ------
// Identity block mapping: bm = blockIdx.x (fast) -> XCD i only ever touches
// bm = i mod 8, a 2MB A-slice that stays L2-resident across all bn rounds.
// (R9's XCD swizzle broke this: FETCH 28 -> 200 MB. Do not re-add.)
// 2-phase double-buffer: issue next K-tile's global_load_lds BEFORE computing
// the current tile; one barrier per K-step drains the prefetch + fences reuse.
template <int MODE>
__global__ __launch_bounds__(256) void k_gemm(
    const u16* __restrict__ Ah, const u16* __restrict__ Bh,
    u16* __restrict__ Qh, u16* __restrict__ Kh, u16* __restrict__ Vth,
    float* __restrict__ Cout, const float* __restrict__ bias) {
  __shared__ u16 sA[2][128 * 64];
  __shared__ u16 sB[2][128 * 64];
  const int t = threadIdx.x, lane = t & 63, w = t >> 6;
  const int bm = blockIdx.x, bn = blockIdx.y;
  const int wm = (w >> 1) * 64, wn = (w & 1) * 64;
  const int g = lane >> 4, c = lane & 15;
  const size_t arow0 = (size_t)bm * 128, brow0 = (size_t)bn * 128;

  // staging geometry: thread t covers chunks t + i*256 (i<4): row = r0 + 32i,
  // swizzled col cs (32 % 8 == 0 -> same cs for all i).
  const int r0 = t >> 3, cc0 = t & 7;
  const int cs0 = cc0 ^ (r0 & 7);
  const u16* gA = Ah + (arow0 + r0) * 1024 + cs0 * 8;
  const u16* gB = Bh + (brow0 + r0) * 1024 + cs0 * 8;

  f32x4 acc[4][4] = {};

  // prologue: stage K-tile 0 into buffer 0
  #pragma unroll
  for (int i = 0; i < 4; i++) {
    gl16(gA + (size_t)i * 32768, sA[0] + (size_t)(t + i * 256) * 8);
    gl16(gB + (size_t)i * 32768, sB[0] + (size_t)(t + i * 256) * 8);
  }
  gA += 64; gB += 64;
  __syncthreads();

  for (int kt = 0; kt < 16; kt++) {
    const int cur = kt & 1, nxt = cur ^ 1;
    if (kt + 1 < 16) {                   // prefetch next K-tile across compute
      #pragma unroll
      for (int i = 0; i < 4; i++) {
        gl16(gA + (size_t)i * 32768, sA[nxt] + (size_t)(t + i * 256) * 8);
        gl16(gB + (size_t)i * 32768, sB[nxt] + (size_t)(t + i * 256) * 8);
      }
      gA += 64; gB += 64;
    }
    #pragma unroll
    for (int ks = 0; ks < 2; ks++) {     // two 32-wide K sub-steps per tile
      bf16x8 afh[4], bfh[4];
      #pragma unroll
      for (int mi = 0; mi < 4; mi++) {
        int row = wm + mi * 16 + c;
        afh[mi] = *(const bf16x8*)(sA[cur] + row * 64 + (((ks * 4 + g) ^ (row & 7)) * 8));
      }
      #pragma unroll
      for (int ni = 0; ni < 4; ni++) {
        int row = wn + ni * 16 + c;
        bfh[ni] = *(const bf16x8*)(sB[cur] + row * 64 + (((ks * 4 + g) ^ (row & 7)) * 8));
      }
      #pragma unroll
      for (int mi = 0; mi < 4; mi++)
        #pragma unroll
        for (int ni = 0; ni < 4; ni++)
          acc[mi][ni] = __builtin_amdgcn_mfma_f32_16x16x32_bf16(afh[mi], bfh[ni], acc[mi][ni], 0, 0, 0);
    }
    // drains the prefetch (issued before ~1k cycles of MFMA) + fences reuse
    __syncthreads();
  }

  if (MODE == 0) {                       // QKV scatter
    #pragma unroll
    for (int mi = 0; mi < 4; mi++) {
      int grow0 = bm * 128 + wm + mi * 16 + g * 4;   // m = b*2048+s
      int b = grow0 >> 11, s0 = grow0 & 2047;
      #pragma unroll
      for (int ni = 0; ni < 4; ni++) {
        int gcol = bn * 128 + wn + ni * 16 + c;       // n in [0,3072)
        int which = gcol >> 10, rem = gcol & 1023;
        int hh = rem >> 6, dd = rem & 63;
        if (which == 2) {                              // V -> transposed [B,H,Dh,S]
          u16x4 hv;
          #pragma unroll
          for (int r = 0; r < 4; r++) hv[r] = f2bf(acc[mi][ni][r]);
          size_t off = ((size_t)((b * 16 + hh) * 64 + dd)) * 2048 + s0;
          *(u16x4*)(Vth + off) = hv;
        } else {                                       // Q or K -> [B,H,S,Dh]
          u16* dh = which ? Kh : Qh;
          float sc = which ? 1.0f : QSCALE;
          #pragma unroll
          for (int r = 0; r < 4; r++) {
            size_t off = ((size_t)(b * 16 + hh) * 2048 + (s0 + r)) * 64 + dd;
            dh[off] = f2bf(acc[mi][ni][r] * sc);
          }
        }
      }
    }
  } else {                               // out-proj: +bias, fp32
    #pragma unroll
    for (int mi = 0; mi < 4; mi++) {
      int grow0 = bm * 128 + wm + mi * 16 + g * 4;
      #pragma unroll
      for (int ni = 0; ni < 4; ni++) {
        int gcol = bn * 128 + wn + ni * 16 + c;
        float bb = bias[gcol];
        #pragma unroll
        for (int r = 0; r < 4; r++)
          Cout[(size_t)(grow0 + r) * 1024 + gcol] = acc[mi][ni][r] + bb;
      }
    }
  }
}

// ---------------- K3: block-causal flash attention (v9) ----------------
// grid (64 b*h, 16 qtiles desc); 512 threads = 8 waves, 16 q-rows/wave.
// KVBLK=128. Swapped QK^T with running max FOLDED INTO THE ACCUMULATOR INIT
// (C = -mrun); defer-check is tl <= 8 (p bounded by 2^8; mrun starts at 0).
// exp2 via raw v_exp_f32. Row-sum via MFMA against a ones-vector.
// LDS: K 2x16KB + V 2x16KB = 64KB -> 2 blocks/CU.
__global__ __launch_bounds__(512, 4) void k_attn(
    const u16* __restrict__ Qh, const u16* __restrict__ Kh,
    const u16* __restrict__ Vth, u16* __restrict__ Oh) {
  __shared__ u16 lK[2][128 * 64], lV[2][64 * 128];
  const int t = threadIdx.x, lane = t & 63, w = t >> 6;  // 8 waves
  const int bh = blockIdx.x;             // 0..63
  const int qt = 15 - blockIdx.y;        // longest blocks dispatched first
  const int b = bh >> 4, h = bh & 15;
  const int qrow0 = qt * 128;
  const int kvlen = (qt / 2 + 1) * 256;
  const int g = lane >> 4, c = lane & 15;

  // Q fragments: wave w covers q-rows [qrow0 + w*16, +16); q = c as B-operand
  bf16x8 qf[2];
  {
    const u16* qb = Qh + ((size_t)bh * 2048 + qrow0 + w * 16) * 64;
    #pragma unroll
    for (int ks = 0; ks < 2; ks++)
      qf[ks] = *(const bf16x8*)(qb + (size_t)c * 64 + ks * 32 + g * 8);
  }

  const u16* Kb = Kh + (size_t)bh * 2048 * 64;
  const u16* Vb = Vth + (size_t)bh * 64 * 2048;

  // hoisted LDS read bases (XOR part is row-block independent):
  // K rows (128B): chunk = (ks*4+g) ^ (c&7);  V rows (256B): chunk = (ks*4+g) ^ c
  int kbase[2], vbase[4];
  #pragma unroll
  for (int ks = 0; ks < 2; ks++) kbase[ks] = c * 64 + (((ks * 4 + g) ^ (c & 7)) * 8);
  #pragma unroll
  for (int ks = 0; ks < 4; ks++) vbase[ks] = c * 128 + (((ks * 4 + g) ^ c) * 8);

  // staging: 512 threads x 2 chunks per tile per stream; source pre-swizzled.
  const int kr0 = t >> 3, kcs0 = (t & 7) ^ (kr0 & 7);
  const int vr0 = t >> 4, vcs0 = (t & 15) ^ (vr0 & 15);

  const bf16x8 vones = {(short)0x3F80, (short)0x3F80, (short)0x3F80, (short)0x3F80,
                        (short)0x3F80, (short)0x3F80, (short)0x3F80, (short)0x3F80};

  float mrun = 0.f;                      // defer-max: p bounded by 2^8
  f32x4 lsum = {0.f, 0.f, 0.f, 0.f};     // row-sums, same layout as o rows
  f32x4 o[4] = {};                       // rows q = g*4 + r, col d = di*16+c

  const int ntiles = kvlen >> 7;

  // prologue: stage tile 0 into buffer 0
  gl16(Kb + (size_t)kr0 * 64 + kcs0 * 8, lK[0] + (size_t)t * 8);
  gl16(Kb + (size_t)(kr0 + 64) * 64 + kcs0 * 8, lK[0] + (size_t)(t + 512) * 8);
  gl16(Vb + (size_t)vr0 * 2048 + vcs0 * 8, lV[0] + (size_t)t * 8);
  gl16(Vb + (size_t)(vr0 + 32) * 2048 + vcs0 * 8, lV[0] + (size_t)(t + 512) * 8);
  __syncthreads();

  // prefetch pointers (tile 1), advanced by constant strides
  const u16* gK = Kb + (size_t)(128 + kr0) * 64 + kcs0 * 8;
  const u16* gV = Vb + (size_t)vr0 * 2048 + 128 + vcs0 * 8;

  for (int kt = 0; kt < ntiles; kt++) {
    const int cur = kt & 1, nxt = cur ^ 1;
    if (kt + 1 < ntiles) {               // prefetch next tile across compute
      gl16(gK, lK[nxt] + (size_t)t * 8);
      gl16(gK + 64 * 64, lK[nxt] + (size_t)(t + 512) * 8);
      gl16(gV, lV[nxt] + (size_t)t * 8);
      gl16(gV + 32 * 2048, lV[nxt] + (size_t)(t + 512) * 8);
      gK += 128 * 64;  gV += 128;
    }

    // S^T - mrun = mfma(A=K, B=Q, C=-mrun): lane holds q=c, kv=ni*16+g*4+r
    f32x4 s[8];
    #pragma unroll
    for (int ni = 0; ni < 8; ni++)
      s[ni] = (f32x4){-mrun, -mrun, -mrun, -mrun};
    __builtin_amdgcn_s_setprio(1);
    #pragma unroll
    for (int ni = 0; ni < 8; ni++)
      #pragma unroll
      for (int ks = 0; ks < 2; ks++) {
        bf16x8 kf = *(const bf16x8*)(lK[cur] + ni * 1024 + kbase[ks]);
        s[ni] = __builtin_amdgcn_mfma_f32_16x16x32_bf16(kf, qf[ks], s[ni], 0, 0, 0);
      }
    __builtin_amdgcn_s_setprio(0);

    // defer-max: lane-local partial max of the shifted scores
    float tl = fmaxf(fmaxf(fmaxf(fmax4(s[0]), fmax4(s[1])), fmaxf(fmax4(s[2]), fmax4(s[3]))),
                     fmaxf(fmaxf(fmax4(s[4]), fmax4(s[5])), fmaxf(fmax4(s[6]), fmax4(s[7]))));
    if (!__all(tl <= 8.0f)) {            // rare: large max jump
      float tm = fmaxf(tl, __shfl_xor(tl, 16));
      tm = fmaxf(tm, __shfl_xor(tm, 32));     // full row max across g-lanes
      float delta = fmaxf(tm, 0.0f);          // per-q (c-layout)
      mrun += delta;
      float al = fexp2(-delta);
      #pragma unroll
      for (int ni = 0; ni < 8; ni++)
        #pragma unroll
        for (int r = 0; r < 4; r++) s[ni][r] -= delta;
      #pragma unroll
      for (int r = 0; r < 4; r++) {
        float ar = __shfl(al, g * 4 + r);     // alpha for o-row q = g*4+r
        lsum[r] *= ar;
        #pragma unroll
        for (int di = 0; di < 4; di++) o[di][r] *= ar;
      }
    }

    // p = exp2(s) -> bf16 pack -> permlane -> PV A-frags
    bf16x8 pa[4];
    #pragma unroll
    for (int ks = 0; ks < 4; ks++) {
      unsigned int e0 = cvtpk(fexp2(s[2 * ks][0]), fexp2(s[2 * ks][1]));
      unsigned int e1 = cvtpk(fexp2(s[2 * ks][2]), fexp2(s[2 * ks][3]));
      unsigned int f0 = cvtpk(fexp2(s[2 * ks + 1][0]), fexp2(s[2 * ks + 1][1]));
      unsigned int f1 = cvtpk(fexp2(s[2 * ks + 1][2]), fexp2(s[2 * ks + 1][3]));
      asm volatile("v_permlane32_swap_b32 %0, %1" : "+v"(e0), "+v"(f0));
      asm volatile("v_permlane16_swap_b32 %0, %1" : "+v"(e0), "+v"(f0));
      asm volatile("v_permlane32_swap_b32 %0, %1" : "+v"(e1), "+v"(f1));
      asm volatile("v_permlane16_swap_b32 %0, %1" : "+v"(e1), "+v"(f1));
      union { u32x4 u; bf16x8 bv; } cvu;
      cvu.u = (u32x4){e0, e1, f0, f1};
      pa[ks] = cvu.bv;                   // P[q=c, kv=ks*32+g*8+j], j=0..7
    }

    // PV: O += P * V; row-sum via ones-MFMA (lands in o's lane layout)
    __builtin_amdgcn_s_setprio(1);
    #pragma unroll
    for (int di = 0; di < 4; di++)
      #pragma unroll
      for (int ks = 0; ks < 4; ks++) {
        bf16x8 vf = *(const bf16x8*)(lV[cur] + di * 2048 + vbase[ks]);
        o[di] = __builtin_amdgcn_mfma_f32_16x16x32_bf16(pa[ks], vf, o[di], 0, 0, 0);
      }
    #pragma unroll
    for (int ks = 0; ks < 4; ks++)
      lsum = __builtin_amdgcn_mfma_f32_16x16x32_bf16(pa[ks], vones, lsum, 0, 0, 0);
    __builtin_amdgcn_s_setprio(0);

    // drains the prefetch (issued ~1k cycles ago) and fences buffer reuse
    __syncthreads();
  }

  // epilogue: normalize (lsum already in o layout), write attnout bf16
  #pragma unroll
  for (int r = 0; r < 4; r++) {
    float ir = 1.0f / lsum[r];
    int srow = qrow0 + w * 16 + g * 4 + r;
    size_t rowo = ((size_t)b * 2048 + srow) * 1024 + h * 64;
    #pragma unroll
    for (int di = 0; di < 4; di++)
      Oh[rowo + di * 16 + c] = f2bf(o[di][r] * ir);
  }
}

// ---------------- launch ----------------
extern "C" void kernel_launch(void* const* d_in, const int* in_sizes, int n_in,
                              void* d_out, int out_size, void* d_ws, size_t ws_size,
                              hipStream_t stream) {
  const float* x     = (const float*)d_in[0];
  const float* gamma = (const float*)d_in[1];
  const float* beta  = (const float*)d_in[2];
  const float* Wqkv  = (const float*)d_in[3];
  const float* Wout  = (const float*)d_in[4];
  const float* bout  = (const float*)d_in[5];
  float* out = (float*)d_out;

  char* ws = (char*)d_ws;
  size_t off = 0;
  auto alloc = [&](size_t bytes) { char* p = ws + off; off += (bytes + 255) & ~(size_t)255; return p; };
  const size_t SZ_XN = (size_t)8192 * 1024 * 2;         // 16MB
  const size_t SZ_WQ = (size_t)3072 * 1024 * 2;         // 6MB
  const size_t SZ_WO = (size_t)1024 * 1024 * 2;         // 2MB
  const size_t SZ_QKV = (size_t)4 * 16 * 2048 * 64 * 2; // 16MB
  u16* xnh  = (u16*)alloc(SZ_XN);   // also attnout (bf16) after attention
  u16* wqth = (u16*)alloc(SZ_WQ);
  u16* woth = (u16*)alloc(SZ_WO);
  u16* Qh  = (u16*)alloc(SZ_QKV);
  u16* Kh  = (u16*)alloc(SZ_QKV);
  u16* Vth = (u16*)alloc(SZ_QKV);
  if (off > ws_size) return;  // workspace too small -> fail visibly (poisoned out)

  k_ln_split<<<8192, 256, 0, stream>>>(x, gamma, beta, xnh);
  k_wsplit_t<<<dim3(96, 32), 256, 0, stream>>>(Wqkv, wqth, 1024, 3072);
  k_wsplit_t<<<dim3(32, 32), 256, 0, stream>>>(Wout, woth, 1024, 1024);
  // QKV projection: one pure-bf16 GEMM over all 3072 columns
  k_gemm<0><<<dim3(64, 24), 256, 0, stream>>>(xnh, wqth,
                                              Qh, Kh, Vth, nullptr, nullptr);
  // attnout (bf16) reuses the xn buffer (xn is dead after the QKV GEMM)
  k_attn<<<dim3(64, 16), 512, 0, stream>>>(Qh, Kh, Vth, xnh);
  k_gemm<1><<<dim3(64, 8), 256, 0, stream>>>(xnh, woth,
                                             nullptr, nullptr, nullptr,
                                             out, bout);
}

// Round 13
// 158.762 us; speedup vs baseline: 1.0327x; 1.0327x over previous
//
#include <hip/hip_runtime.h>
#include <stdint.h>

typedef unsigned short u16;
typedef __attribute__((ext_vector_type(8))) short bf16x8;
typedef __attribute__((ext_vector_type(4))) float f32x4;
typedef __attribute__((ext_vector_type(4))) unsigned short u16x4;
typedef __attribute__((ext_vector_type(4))) unsigned int u32x4;

#define DEVI static __device__ __forceinline__

// dots*scale folded into Q, with base-2 softmax: exp(s) == exp2(s*log2e)
#define QSCALE (0.125f * 1.4426950408889634f)

DEVI u16 f2bf(float f) {
  union { float f; unsigned int u; } v; v.f = f;
  unsigned int u = v.u + 0x7fffu + ((v.u >> 16) & 1u);
  return (u16)(u >> 16);
}
DEVI void gl16(const void* g, void* l) {
  __builtin_amdgcn_global_load_lds(
      (__attribute__((address_space(1))) void*)g,
      (__attribute__((address_space(3))) void*)l, 16, 0, 0);
}
// packed f32x2 -> bf16x2 (RNE), lo=bf16(a), hi=bf16(b)
DEVI unsigned int cvtpk(float a, float b) {
  unsigned int r;
  asm("v_cvt_pk_bf16_f32 %0, %1, %2" : "=v"(r) : "v"(a), "v"(b));
  return r;
}
// raw v_exp_f32 (flushes f32 denormal results -- fine here)
DEVI float fexp2(float x) {
  float r;
  asm("v_exp_f32 %0, %1\n\ts_nop 0" : "=v"(r) : "v"(x));
  return r;
}
DEVI float fmax4(f32x4 v) {
  return fmaxf(fmaxf(v[0], v[1]), fmaxf(v[2], v[3]));
}

// ---------------- K1: LayerNorm -> bf16 ----------------
__global__ __launch_bounds__(256) void k_ln_split(
    const float* __restrict__ x, const float* __restrict__ gamma,
    const float* __restrict__ beta, u16* __restrict__ xh) {
  const int row = blockIdx.x;
  const int t = threadIdx.x;
  const float4* xr = (const float4*)(x + (size_t)row * 1024);
  float4 v = xr[t];
  float s = v.x + v.y + v.z + v.w;
  float s2 = v.x * v.x + v.y * v.y + v.z * v.z + v.w * v.w;
  #pragma unroll
  for (int m = 1; m < 64; m <<= 1) { s += __shfl_xor(s, m); s2 += __shfl_xor(s2, m); }
  __shared__ float ls[4], ls2[4];
  if ((t & 63) == 0) { ls[t >> 6] = s; ls2[t >> 6] = s2; }
  __syncthreads();
  s = ls[0] + ls[1] + ls[2] + ls[3];
  s2 = ls2[0] + ls2[1] + ls2[2] + ls2[3];
  float mu = s * (1.0f / 1024.0f);
  float var = s2 * (1.0f / 1024.0f) - mu * mu;
  float rstd = rsqrtf(var + 1e-5f);
  float4 g = ((const float4*)gamma)[t];
  float4 b = ((const float4*)beta)[t];
  float xv[4] = {v.x, v.y, v.z, v.w};
  float gg[4] = {g.x, g.y, g.z, g.w};
  float bb[4] = {b.x, b.y, b.z, b.w};
  u16x4 hv;
  #pragma unroll
  for (int i = 0; i < 4; i++) {
    float xn = (xv[i] - mu) * rstd * gg[i] + bb[i];
    hv[i] = f2bf(xn);
  }
  ((u16x4*)xh)[(size_t)row * 256 + t] = hv;
}

// ---------------- K1b: transpose weights, fp32 -> bf16 ----------------
__global__ __launch_bounds__(256) void k_wsplit_t(
    const float* __restrict__ W, u16* __restrict__ Wth, int K, int N) {
  __shared__ float tile[32][33];
  const int t = threadIdx.x;
  const int tx = t & 31, ty = t >> 5;
  #pragma unroll
  for (int i = 0; i < 4; i++) {
    int k = blockIdx.y * 32 + ty + i * 8;
    int n = blockIdx.x * 32 + tx;
    tile[ty + i * 8][tx] = W[(size_t)k * N + n];
  }
  __syncthreads();
  #pragma unroll
  for (int i = 0; i < 4; i++) {
    int n = blockIdx.x * 32 + ty + i * 8;
    int k = blockIdx.y * 32 + tx;
    Wth[(size_t)n * K + k] = f2bf(tile[tx][ty + i * 8]);
  }
}

// ---------------- K2: QKV GEMM, 256x256 tile, 4-phase counted-vmcnt ------
// 512 threads = 8 waves (2M x 4N), wave tile 128x64, BK=64, K=1024 (16 tiles).
// LDS 128KB: per-unit double-buffered. Units are consumption-striped:
//   A-unit u = rows { r : (r>>6)&1 == u }   (read at phases 2u, 2u+1)
//   B-unit u = rows { r : (r>>5)&1 == u }   (read at phases u, u+2)
// Per phase: ds_read quadrant frags; stage ONE unit (2 gl16); vmcnt(6)
// (allow newest 3 units in flight); raw s_barrier (NO vmcnt(0) drain).
// Stage schedule: t.p0 -> Au1(t+1); t.p1 -> Bu1(t+1); t.p2 -> Au0(t+2);
// t.p3 -> Bu0(t+2).  All slot overwrites are barrier-separated from their
// last readers (verified per-unit).  Tail (t>=14): full drain.
__global__ __launch_bounds__(512, 2) void k_gemmq(
    const u16* __restrict__ Ah, const u16* __restrict__ Bh,
    u16* __restrict__ Qh, u16* __restrict__ Kh, u16* __restrict__ Vth) {
  __shared__ u16 sA[2][256 * 64];
  __shared__ u16 sB[2][256 * 64];
  const int t = threadIdx.x, lane = t & 63, w = t >> 6;
  const int bm = blockIdx.x, bn = blockIdx.y;
  const int wm2 = w >> 2, wn4 = w & 3;      // 2 M-waves x 4 N-waves
  const int g = lane >> 4, c = lane & 15;
  const size_t arow0 = (size_t)bm * 256, brow0 = (size_t)bn * 256;

  // staging geometry (thread-uniform swizzle: pre-swizzled SOURCE, linear LDS)
  const int sr = t >> 3;                    // 0..63
  const int scs = (t & 7) ^ (sr & 7);       // A: row&7 == sr&7 for all spans
  const int brs = (t >> 3) & 31;            // B row-in-span
  const int bcs = (t & 7) ^ (brs & 7);      // B swizzled chunk
  const int bsj = t >> 8;                   // B span parity from thread id

  f32x4 acc[8][4] = {};

  // A-unit u of K-tile kt -> buffer b: rows u*64+sr and 128+u*64+sr
#define STAGE_A(u, kt, b) do { \
    int rA0 = (u) * 64 + sr, rA1 = 128 + rA0; \
    gl16(Ah + (arow0 + rA0) * 1024 + (size_t)(kt) * 64 + scs * 8, \
         sA[b] + (size_t)((u) * 512 + t) * 8); \
    gl16(Ah + (arow0 + rA1) * 1024 + (size_t)(kt) * 64 + scs * 8, \
         sA[b] + (size_t)(1024 + (u) * 512 + t) * 8); \
  } while (0)
  // B-unit u: 4 spans of 32 rows at u*32 + s*64; thread covers spans
  // (bsj) and (bsj+2) via j=0,1
#define STAGE_B(u, kt, b) do { \
    int s0_ = bsj, s1_ = bsj + 2; \
    int rB0 = (u) * 32 + s0_ * 64 + brs, rB1 = (u) * 32 + s1_ * 64 + brs; \
    gl16(Bh + (brow0 + rB0) * 1024 + (size_t)(kt) * 64 + bcs * 8, \
         sB[b] + (size_t)(rB0 * 8 + (t & 7)) * 8); \
    gl16(Bh + (brow0 + rB1) * 1024 + (size_t)(kt) * 64 + bcs * 8, \
         sB[b] + (size_t)(rB1 * 8 + (t & 7)) * 8); \
  } while (0)
#define PWAIT(tail) do { \
    if (tail) asm volatile("s_waitcnt vmcnt(0)" ::: "memory"); \
    else      asm volatile("s_waitcnt vmcnt(6)" ::: "memory"); \
    __builtin_amdgcn_s_barrier(); \
    __builtin_amdgcn_sched_barrier(0); \
  } while (0)

  // prologue: tile0 fully + tile1's unit0s (6 units, issue order matters)
  STAGE_A(0, 0, 0); STAGE_B(0, 0, 0);
  STAGE_A(1, 0, 0); STAGE_B(1, 0, 0);
  STAGE_A(0, 1, 1); STAGE_B(0, 1, 1);
  PWAIT(0);

  bf16x8 af[8], bf0[4], bf1[4];
  for (int kt = 0; kt < 16; kt++) {
    const int cur = kt & 1;
    const int tail = (kt >= 14);
    const u16* A_ = sA[cur];
    const u16* B_ = sB[cur];

    // ---- phase 0: quadrant (mq=0, nq=0) ----
    #pragma unroll
    for (int mi = 0; mi < 4; mi++)
      #pragma unroll
      for (int ks = 0; ks < 2; ks++) {
        int row = wm2 * 128 + mi * 16 + c;
        af[mi * 2 + ks] = *(const bf16x8*)(A_ + row * 64 + (((ks * 4 + g) ^ (row & 7)) * 8));
      }
    #pragma unroll
    for (int ni = 0; ni < 2; ni++)
      #pragma unroll
      for (int ks = 0; ks < 2; ks++) {
        int row = wn4 * 64 + ni * 16 + c;
        bf0[ni * 2 + ks] = *(const bf16x8*)(B_ + row * 64 + (((ks * 4 + g) ^ (row & 7)) * 8));
      }
    if (kt + 1 < 16) STAGE_A(1, kt + 1, (kt + 1) & 1);
    PWAIT(tail);
    __builtin_amdgcn_s_setprio(1);
    #pragma unroll
    for (int mi = 0; mi < 4; mi++)
      #pragma unroll
      for (int ni = 0; ni < 2; ni++)
        #pragma unroll
        for (int ks = 0; ks < 2; ks++)
          acc[mi][ni] = __builtin_amdgcn_mfma_f32_16x16x32_bf16(af[mi * 2 + ks], bf0[ni * 2 + ks], acc[mi][ni], 0, 0, 0);
    __builtin_amdgcn_s_setprio(0);

    // ---- phase 1: quadrant (mq=0, nq=1) ----
    #pragma unroll
    for (int ni = 0; ni < 2; ni++)
      #pragma unroll
      for (int ks = 0; ks < 2; ks++) {
        int row = wn4 * 64 + 32 + ni * 16 + c;
        bf1[ni * 2 + ks] = *(const bf16x8*)(B_ + row * 64 + (((ks * 4 + g) ^ (row & 7)) * 8));
      }
    if (kt + 1 < 16) STAGE_B(1, kt + 1, (kt + 1) & 1);
    PWAIT(tail);
    __builtin_amdgcn_s_setprio(1);
    #pragma unroll
    for (int mi = 0; mi < 4; mi++)
      #pragma unroll
      for (int ni = 0; ni < 2; ni++)
        #pragma unroll
        for (int ks = 0; ks < 2; ks++)
          acc[mi][2 + ni] = __builtin_amdgcn_mfma_f32_16x16x32_bf16(af[mi * 2 + ks], bf1[ni * 2 + ks], acc[mi][2 + ni], 0, 0, 0);
    __builtin_amdgcn_s_setprio(0);

    // ---- phase 2: quadrant (mq=1, nq=0) ----
    #pragma unroll
    for (int mi = 0; mi < 4; mi++)
      #pragma unroll
      for (int ks = 0; ks < 2; ks++) {
        int row = wm2 * 128 + 64 + mi * 16 + c;
        af[mi * 2 + ks] = *(const bf16x8*)(A_ + row * 64 + (((ks * 4 + g) ^ (row & 7)) * 8));
      }
    if (kt + 2 < 16) STAGE_A(0, kt + 2, cur);
    PWAIT(tail);
    __builtin_amdgcn_s_setprio(1);
    #pragma unroll
    for (int mi = 0; mi < 4; mi++)
      #pragma unroll
      for (int ni = 0; ni < 2; ni++)
        #pragma unroll
        for (int ks = 0; ks < 2; ks++)
          acc[4 + mi][ni] = __builtin_amdgcn_mfma_f32_16x16x32_bf16(af[mi * 2 + ks], bf0[ni * 2 + ks], acc[4 + mi][ni], 0, 0, 0);
    __builtin_amdgcn_s_setprio(0);

    // ---- phase 3: quadrant (mq=1, nq=1) ----
    if (kt + 2 < 16) STAGE_B(0, kt + 2, cur);
    PWAIT(tail);
    __builtin_amdgcn_s_setprio(1);
    #pragma unroll
    for (int mi = 0; mi < 4; mi++)
      #pragma unroll
      for (int ni = 0; ni < 2; ni++)
        #pragma unroll
        for (int ks = 0; ks < 2; ks++)
          acc[4 + mi][2 + ni] = __builtin_amdgcn_mfma_f32_16x16x32_bf16(af[mi * 2 + ks], bf1[ni * 2 + ks], acc[4 + mi][2 + ni], 0, 0, 0);
    __builtin_amdgcn_s_setprio(0);
  }

  // epilogue: QKV scatter (Q scaled, K, V transposed)
  #pragma unroll
  for (int am = 0; am < 8; am++) {
    int grow0 = bm * 256 + wm2 * 128 + (am >> 2) * 64 + (am & 3) * 16 + g * 4;
    int b = grow0 >> 11, s0 = grow0 & 2047;
    #pragma unroll
    for (int an = 0; an < 4; an++) {
      int gcol = bn * 256 + wn4 * 64 + (an >> 1) * 32 + (an & 1) * 16 + c;
      int which = gcol >> 10, rem = gcol & 1023;
      int hh = rem >> 6, dd = rem & 63;
      if (which == 2) {                    // V -> transposed [B,H,Dh,S]
        u16x4 hv;
        #pragma unroll
        for (int r = 0; r < 4; r++) hv[r] = f2bf(acc[am][an][r]);
        size_t off = ((size_t)((b * 16 + hh) * 64 + dd)) * 2048 + s0;
        *(u16x4*)(Vth + off) = hv;
      } else {                             // Q or K -> [B,H,S,Dh]
        u16* dh = which ? Kh : Qh;
        float sc = which ? 1.0f : QSCALE;
        #pragma unroll
        for (int r = 0; r < 4; r++) {
          size_t off = ((size_t)(b * 16 + hh) * 2048 + (s0 + r)) * 64 + dd;
          dh[off] = f2bf(acc[am][an][r] * sc);
        }
      }
    }
  }
#undef STAGE_A
#undef STAGE_B
#undef PWAIT
}

// ---------------- K4: out-proj GEMM (128x128, 2-stage) ----------------
__global__ __launch_bounds__(256) void k_gemmo(
    const u16* __restrict__ Ah, const u16* __restrict__ Bh,
    float* __restrict__ Cout, const float* __restrict__ bias) {
  __shared__ u16 sA[2][128 * 64];
  __shared__ u16 sB[2][128 * 64];
  const int t = threadIdx.x, lane = t & 63, w = t >> 6;
  const int bm = blockIdx.x, bn = blockIdx.y;
  const int wm = (w >> 1) * 64, wn = (w & 1) * 64;
  const int g = lane >> 4, c = lane & 15;
  const size_t arow0 = (size_t)bm * 128, brow0 = (size_t)bn * 128;

  const int r0 = t >> 3, cc0 = t & 7;
  const int cs0 = cc0 ^ (r0 & 7);
  const u16* gA = Ah + (arow0 + r0) * 1024 + cs0 * 8;
  const u16* gB = Bh + (brow0 + r0) * 1024 + cs0 * 8;

  f32x4 acc[4][4] = {};

  #pragma unroll
  for (int i = 0; i < 4; i++) {
    gl16(gA + (size_t)i * 32768, sA[0] + (size_t)(t + i * 256) * 8);
    gl16(gB + (size_t)i * 32768, sB[0] + (size_t)(t + i * 256) * 8);
  }
  gA += 64; gB += 64;
  __syncthreads();

  for (int kt = 0; kt < 16; kt++) {
    const int cur = kt & 1, nxt = cur ^ 1;
    if (kt + 1 < 16) {
      #pragma unroll
      for (int i = 0; i < 4; i++) {
        gl16(gA + (size_t)i * 32768, sA[nxt] + (size_t)(t + i * 256) * 8);
        gl16(gB + (size_t)i * 32768, sB[nxt] + (size_t)(t + i * 256) * 8);
      }
      gA += 64; gB += 64;
    }
    #pragma unroll
    for (int ks = 0; ks < 2; ks++) {
      bf16x8 afh[4], bfh[4];
      #pragma unroll
      for (int mi = 0; mi < 4; mi++) {
        int row = wm + mi * 16 + c;
        afh[mi] = *(const bf16x8*)(sA[cur] + row * 64 + (((ks * 4 + g) ^ (row & 7)) * 8));
      }
      #pragma unroll
      for (int ni = 0; ni < 4; ni++) {
        int row = wn + ni * 16 + c;
        bfh[ni] = *(const bf16x8*)(sB[cur] + row * 64 + (((ks * 4 + g) ^ (row & 7)) * 8));
      }
      #pragma unroll
      for (int mi = 0; mi < 4; mi++)
        #pragma unroll
        for (int ni = 0; ni < 4; ni++)
          acc[mi][ni] = __builtin_amdgcn_mfma_f32_16x16x32_bf16(afh[mi], bfh[ni], acc[mi][ni], 0, 0, 0);
    }
    __syncthreads();
  }

  #pragma unroll
  for (int mi = 0; mi < 4; mi++) {
    int grow0 = bm * 128 + wm + mi * 16 + g * 4;
    #pragma unroll
    for (int ni = 0; ni < 4; ni++) {
      int gcol = bn * 128 + wn + ni * 16 + c;
      float bb = bias[gcol];
      #pragma unroll
      for (int r = 0; r < 4; r++)
        Cout[(size_t)(grow0 + r) * 1024 + gcol] = acc[mi][ni][r] + bb;
    }
  }
}

// ---------------- K3: block-causal flash attention (v9, unchanged) ----------
__global__ __launch_bounds__(512, 4) void k_attn(
    const u16* __restrict__ Qh, const u16* __restrict__ Kh,
    const u16* __restrict__ Vth, u16* __restrict__ Oh) {
  __shared__ u16 lK[2][128 * 64], lV[2][64 * 128];
  const int t = threadIdx.x, lane = t & 63, w = t >> 6;
  const int bh = blockIdx.x;
  const int qt = 15 - blockIdx.y;
  const int b = bh >> 4, h = bh & 15;
  const int qrow0 = qt * 128;
  const int kvlen = (qt / 2 + 1) * 256;
  const int g = lane >> 4, c = lane & 15;

  bf16x8 qf[2];
  {
    const u16* qb = Qh + ((size_t)bh * 2048 + qrow0 + w * 16) * 64;
    #pragma unroll
    for (int ks = 0; ks < 2; ks++)
      qf[ks] = *(const bf16x8*)(qb + (size_t)c * 64 + ks * 32 + g * 8);
  }

  const u16* Kb = Kh + (size_t)bh * 2048 * 64;
  const u16* Vb = Vth + (size_t)bh * 64 * 2048;

  int kbase[2], vbase[4];
  #pragma unroll
  for (int ks = 0; ks < 2; ks++) kbase[ks] = c * 64 + (((ks * 4 + g) ^ (c & 7)) * 8);
  #pragma unroll
  for (int ks = 0; ks < 4; ks++) vbase[ks] = c * 128 + (((ks * 4 + g) ^ c) * 8);

  const int kr0 = t >> 3, kcs0 = (t & 7) ^ (kr0 & 7);
  const int vr0 = t >> 4, vcs0 = (t & 15) ^ (vr0 & 15);

  const bf16x8 vones = {(short)0x3F80, (short)0x3F80, (short)0x3F80, (short)0x3F80,
                        (short)0x3F80, (short)0x3F80, (short)0x3F80, (short)0x3F80};

  float mrun = 0.f;
  f32x4 lsum = {0.f, 0.f, 0.f, 0.f};
  f32x4 o[4] = {};

  const int ntiles = kvlen >> 7;

  gl16(Kb + (size_t)kr0 * 64 + kcs0 * 8, lK[0] + (size_t)t * 8);
  gl16(Kb + (size_t)(kr0 + 64) * 64 + kcs0 * 8, lK[0] + (size_t)(t + 512) * 8);
  gl16(Vb + (size_t)vr0 * 2048 + vcs0 * 8, lV[0] + (size_t)t * 8);
  gl16(Vb + (size_t)(vr0 + 32) * 2048 + vcs0 * 8, lV[0] + (size_t)(t + 512) * 8);
  __syncthreads();

  const u16* gK = Kb + (size_t)(128 + kr0) * 64 + kcs0 * 8;
  const u16* gV = Vb + (size_t)vr0 * 2048 + 128 + vcs0 * 8;

  for (int kt = 0; kt < ntiles; kt++) {
    const int cur = kt & 1, nxt = cur ^ 1;
    if (kt + 1 < ntiles) {
      gl16(gK, lK[nxt] + (size_t)t * 8);
      gl16(gK + 64 * 64, lK[nxt] + (size_t)(t + 512) * 8);
      gl16(gV, lV[nxt] + (size_t)t * 8);
      gl16(gV + 32 * 2048, lV[nxt] + (size_t)(t + 512) * 8);
      gK += 128 * 64;  gV += 128;
    }

    f32x4 s[8];
    #pragma unroll
    for (int ni = 0; ni < 8; ni++)
      s[ni] = (f32x4){-mrun, -mrun, -mrun, -mrun};
    __builtin_amdgcn_s_setprio(1);
    #pragma unroll
    for (int ni = 0; ni < 8; ni++)
      #pragma unroll
      for (int ks = 0; ks < 2; ks++) {
        bf16x8 kf = *(const bf16x8*)(lK[cur] + ni * 1024 + kbase[ks]);
        s[ni] = __builtin_amdgcn_mfma_f32_16x16x32_bf16(kf, qf[ks], s[ni], 0, 0, 0);
      }
    __builtin_amdgcn_s_setprio(0);

    float tl = fmaxf(fmaxf(fmaxf(fmax4(s[0]), fmax4(s[1])), fmaxf(fmax4(s[2]), fmax4(s[3]))),
                     fmaxf(fmaxf(fmax4(s[4]), fmax4(s[5])), fmaxf(fmax4(s[6]), fmax4(s[7]))));
    if (!__all(tl <= 8.0f)) {
      float tm = fmaxf(tl, __shfl_xor(tl, 16));
      tm = fmaxf(tm, __shfl_xor(tm, 32));
      float delta = fmaxf(tm, 0.0f);
      mrun += delta;
      float al = fexp2(-delta);
      #pragma unroll
      for (int ni = 0; ni < 8; ni++)
        #pragma unroll
        for (int r = 0; r < 4; r++) s[ni][r] -= delta;
      #pragma unroll
      for (int r = 0; r < 4; r++) {
        float ar = __shfl(al, g * 4 + r);
        lsum[r] *= ar;
        #pragma unroll
        for (int di = 0; di < 4; di++) o[di][r] *= ar;
      }
    }

    bf16x8 pa[4];
    #pragma unroll
    for (int ks = 0; ks < 4; ks++) {
      unsigned int e0 = cvtpk(fexp2(s[2 * ks][0]), fexp2(s[2 * ks][1]));
      unsigned int e1 = cvtpk(fexp2(s[2 * ks][2]), fexp2(s[2 * ks][3]));
      unsigned int f0 = cvtpk(fexp2(s[2 * ks + 1][0]), fexp2(s[2 * ks + 1][1]));
      unsigned int f1 = cvtpk(fexp2(s[2 * ks + 1][2]), fexp2(s[2 * ks + 1][3]));
      asm volatile("v_permlane32_swap_b32 %0, %1" : "+v"(e0), "+v"(f0));
      asm volatile("v_permlane16_swap_b32 %0, %1" : "+v"(e0), "+v"(f0));
      asm volatile("v_permlane32_swap_b32 %0, %1" : "+v"(e1), "+v"(f1));
      asm volatile("v_permlane16_swap_b32 %0, %1" : "+v"(e1), "+v"(f1));
      union { u32x4 u; bf16x8 bv; } cvu;
      cvu.u = (u32x4){e0, e1, f0, f1};
      pa[ks] = cvu.bv;
    }

    __builtin_amdgcn_s_setprio(1);
    #pragma unroll
    for (int di = 0; di < 4; di++)
      #pragma unroll
      for (int ks = 0; ks < 4; ks++) {
        bf16x8 vf = *(const bf16x8*)(lV[cur] + di * 2048 + vbase[ks]);
        o[di] = __builtin_amdgcn_mfma_f32_16x16x32_bf16(pa[ks], vf, o[di], 0, 0, 0);
      }
    #pragma unroll
    for (int ks = 0; ks < 4; ks++)
      lsum = __builtin_amdgcn_mfma_f32_16x16x32_bf16(pa[ks], vones, lsum, 0, 0, 0);
    __builtin_amdgcn_s_setprio(0);

    __syncthreads();
  }

  #pragma unroll
  for (int r = 0; r < 4; r++) {
    float ir = 1.0f / lsum[r];
    int srow = qrow0 + w * 16 + g * 4 + r;
    size_t rowo = ((size_t)b * 2048 + srow) * 1024 + h * 64;
    #pragma unroll
    for (int di = 0; di < 4; di++)
      Oh[rowo + di * 16 + c] = f2bf(o[di][r] * ir);
  }
}

// ---------------- launch ----------------
extern "C" void kernel_launch(void* const* d_in, const int* in_sizes, int n_in,
                              void* d_out, int out_size, void* d_ws, size_t ws_size,
                              hipStream_t stream) {
  const float* x     = (const float*)d_in[0];
  const float* gamma = (const float*)d_in[1];
  const float* beta  = (const float*)d_in[2];
  const float* Wqkv  = (const float*)d_in[3];
  const float* Wout  = (const float*)d_in[4];
  const float* bout  = (const float*)d_in[5];
  float* out = (float*)d_out;

  char* ws = (char*)d_ws;
  size_t off = 0;
  auto alloc = [&](size_t bytes) { char* p = ws + off; off += (bytes + 255) & ~(size_t)255; return p; };
  const size_t SZ_XN = (size_t)8192 * 1024 * 2;
  const size_t SZ_WQ = (size_t)3072 * 1024 * 2;
  const size_t SZ_WO = (size_t)1024 * 1024 * 2;
  const size_t SZ_QKV = (size_t)4 * 16 * 2048 * 64 * 2;
  u16* xnh  = (u16*)alloc(SZ_XN);   // also attnout (bf16) after attention
  u16* wqth = (u16*)alloc(SZ_WQ);
  u16* woth = (u16*)alloc(SZ_WO);
  u16* Qh  = (u16*)alloc(SZ_QKV);
  u16* Kh  = (u16*)alloc(SZ_QKV);
  u16* Vth = (u16*)alloc(SZ_QKV);
  if (off > ws_size) return;

  k_ln_split<<<8192, 256, 0, stream>>>(x, gamma, beta, xnh);
  k_wsplit_t<<<dim3(96, 32), 256, 0, stream>>>(Wqkv, wqth, 1024, 3072);
  k_wsplit_t<<<dim3(32, 32), 256, 0, stream>>>(Wout, woth, 1024, 1024);
  // QKV projection: 256x256-tile 4-phase counted-vmcnt GEMM
  k_gemmq<<<dim3(32, 12), 512, 0, stream>>>(xnh, wqth, Qh, Kh, Vth);
  // attnout (bf16) reuses the xn buffer (xn is dead after the QKV GEMM)
  k_attn<<<dim3(64, 16), 512, 0, stream>>>(Qh, Kh, Vth, xnh);
  k_gemmo<<<dim3(64, 8), 256, 0, stream>>>(xnh, woth, out, bout);
}

// Round 14
// 158.427 us; speedup vs baseline: 1.0349x; 1.0021x over previous
//
#include <hip/hip_runtime.h>
#include <stdint.h>

typedef unsigned short u16;
typedef __attribute__((ext_vector_type(8))) short bf16x8;
typedef __attribute__((ext_vector_type(4))) float f32x4;
typedef __attribute__((ext_vector_type(4))) unsigned short u16x4;
typedef __attribute__((ext_vector_type(4))) unsigned int u32x4;

#define DEVI static __device__ __forceinline__

// dots*scale folded into Q, with base-2 softmax: exp(s) == exp2(s*log2e)
#define QSCALE (0.125f * 1.4426950408889634f)

DEVI u16 f2bf(float f) {
  union { float f; unsigned int u; } v; v.f = f;
  unsigned int u = v.u + 0x7fffu + ((v.u >> 16) & 1u);
  return (u16)(u >> 16);
}
DEVI void gl16(const void* g, void* l) {
  __builtin_amdgcn_global_load_lds(
      (__attribute__((address_space(1))) void*)g,
      (__attribute__((address_space(3))) void*)l, 16, 0, 0);
}
// packed f32x2 -> bf16x2 (RNE), lo=bf16(a), hi=bf16(b)
DEVI unsigned int cvtpk(float a, float b) {
  unsigned int r;
  asm("v_cvt_pk_bf16_f32 %0, %1, %2" : "=v"(r) : "v"(a), "v"(b));
  return r;
}
// raw v_exp_f32 (flushes f32 denormal results -- fine here)
DEVI float fexp2(float x) {
  float r;
  asm("v_exp_f32 %0, %1\n\ts_nop 0" : "=v"(r) : "v"(x));
  return r;
}
DEVI float fmax4(f32x4 v) {
  return fmaxf(fmaxf(v[0], v[1]), fmaxf(v[2], v[3]));
}

// ---------------- K1: LayerNorm -> bf16 ----------------
__global__ __launch_bounds__(256) void k_ln_split(
    const float* __restrict__ x, const float* __restrict__ gamma,
    const float* __restrict__ beta, u16* __restrict__ xh) {
  const int row = blockIdx.x;
  const int t = threadIdx.x;
  const float4* xr = (const float4*)(x + (size_t)row * 1024);
  float4 v = xr[t];
  float s = v.x + v.y + v.z + v.w;
  float s2 = v.x * v.x + v.y * v.y + v.z * v.z + v.w * v.w;
  #pragma unroll
  for (int m = 1; m < 64; m <<= 1) { s += __shfl_xor(s, m); s2 += __shfl_xor(s2, m); }
  __shared__ float ls[4], ls2[4];
  if ((t & 63) == 0) { ls[t >> 6] = s; ls2[t >> 6] = s2; }
  __syncthreads();
  s = ls[0] + ls[1] + ls[2] + ls[3];
  s2 = ls2[0] + ls2[1] + ls2[2] + ls2[3];
  float mu = s * (1.0f / 1024.0f);
  float var = s2 * (1.0f / 1024.0f) - mu * mu;
  float rstd = rsqrtf(var + 1e-5f);
  float4 g = ((const float4*)gamma)[t];
  float4 b = ((const float4*)beta)[t];
  float xv[4] = {v.x, v.y, v.z, v.w};
  float gg[4] = {g.x, g.y, g.z, g.w};
  float bb[4] = {b.x, b.y, b.z, b.w};
  u16x4 hv;
  #pragma unroll
  for (int i = 0; i < 4; i++) {
    float xn = (xv[i] - mu) * rstd * gg[i] + bb[i];
    hv[i] = f2bf(xn);
  }
  ((u16x4*)xh)[(size_t)row * 256 + t] = hv;
}

// ---------------- K1b: transpose weights, fp32 -> bf16 ----------------
__global__ __launch_bounds__(256) void k_wsplit_t(
    const float* __restrict__ W, u16* __restrict__ Wth, int K, int N) {
  __shared__ float tile[32][33];
  const int t = threadIdx.x;
  const int tx = t & 31, ty = t >> 5;
  #pragma unroll
  for (int i = 0; i < 4; i++) {
    int k = blockIdx.y * 32 + ty + i * 8;
    int n = blockIdx.x * 32 + tx;
    tile[ty + i * 8][tx] = W[(size_t)k * N + n];
  }
  __syncthreads();
  #pragma unroll
  for (int i = 0; i < 4; i++) {
    int n = blockIdx.x * 32 + ty + i * 8;
    int k = blockIdx.y * 32 + tx;
    Wth[(size_t)n * K + k] = f2bf(tile[tx][ty + i * 8]);
  }
}

// ---------------- K2: QKV GEMM, 256x256 tile, 4-phase, counted vmcnt ------
// 512 threads = 8 waves (2M x 4N), wave tile 128x64, BK=64, K=1024 (16 tiles).
// T4 discipline (m201 template): vmcnt(6) ONCE per K-tile at phase 0 (allows
// the newest 3 units to stay in flight across barriers); phases 1-3 get a
// bare barrier + lgkmcnt(0). NO sched_barrier (ds_reads are compiler-visible;
// deps tracked). Tail kt>=14: vmcnt(0) at phase 0.
// Proof of vmcnt(6)@p0(t): newest-6 gl16 = units {Au0(t+1),Bu0(t+1),Au1(t+1)};
// all tile-t units are older -> forced landed; barriers publish.
__global__ __launch_bounds__(512, 2) void k_gemmq(
    const u16* __restrict__ Ah, const u16* __restrict__ Bh,
    u16* __restrict__ Qh, u16* __restrict__ Kh, u16* __restrict__ Vth) {
  __shared__ u16 sA[2][256 * 64];
  __shared__ u16 sB[2][256 * 64];
  const int t = threadIdx.x, lane = t & 63, w = t >> 6;
  const int bm = blockIdx.x, bn = blockIdx.y;
  const int wm2 = w >> 2, wn4 = w & 3;      // 2 M-waves x 4 N-waves
  const int g = lane >> 4, c = lane & 15;
  const size_t arow0 = (size_t)bm * 256, brow0 = (size_t)bn * 256;

  // staging geometry (pre-swizzled SOURCE, linear LDS)
  const int sr = t >> 3;                    // 0..63
  const int scs = (t & 7) ^ (sr & 7);
  const int brs = (t >> 3) & 31;
  const int bcs = (t & 7) ^ (brs & 7);
  const int bsj = t >> 8;

  f32x4 acc[8][4] = {};

#define STAGE_A(u, kt, b) do { \
    int rA0 = (u) * 64 + sr, rA1 = 128 + rA0; \
    gl16(Ah + (arow0 + rA0) * 1024 + (size_t)(kt) * 64 + scs * 8, \
         sA[b] + (size_t)((u) * 512 + t) * 8); \
    gl16(Ah + (arow0 + rA1) * 1024 + (size_t)(kt) * 64 + scs * 8, \
         sA[b] + (size_t)(1024 + (u) * 512 + t) * 8); \
  } while (0)
#define STAGE_B(u, kt, b) do { \
    int s0_ = bsj, s1_ = bsj + 2; \
    int rB0 = (u) * 32 + s0_ * 64 + brs, rB1 = (u) * 32 + s1_ * 64 + brs; \
    gl16(Bh + (brow0 + rB0) * 1024 + (size_t)(kt) * 64 + bcs * 8, \
         sB[b] + (size_t)(rB0 * 8 + (t & 7)) * 8); \
    gl16(Bh + (brow0 + rB1) * 1024 + (size_t)(kt) * 64 + bcs * 8, \
         sB[b] + (size_t)(rB1 * 8 + (t & 7)) * 8); \
  } while (0)
  // phase 0 wait: counted vmcnt + barrier; loads stay in flight elsewhere
#define PWAIT_V(tail) do { \
    if (tail) asm volatile("s_waitcnt vmcnt(0)" ::: "memory"); \
    else      asm volatile("s_waitcnt vmcnt(6)" ::: "memory"); \
    __builtin_amdgcn_s_barrier(); \
    asm volatile("s_waitcnt lgkmcnt(0)" ::: "memory"); \
  } while (0)
  // phases 1-3: bare barrier (no vmcnt -- prefetch stays outstanding)
#define PWAIT_N() do { \
    __builtin_amdgcn_s_barrier(); \
    asm volatile("s_waitcnt lgkmcnt(0)" ::: "memory"); \
  } while (0)

  // prologue: tile0 fully + tile1's unit0s
  STAGE_A(0, 0, 0); STAGE_B(0, 0, 0);
  STAGE_A(1, 0, 0); STAGE_B(1, 0, 0);
  STAGE_A(0, 1, 1); STAGE_B(0, 1, 1);
  PWAIT_V(0);

  bf16x8 af[8], bf0[4], bf1[4];
  for (int kt = 0; kt < 16; kt++) {
    const int cur = kt & 1;
    const int tail = (kt >= 14);
    const u16* A_ = sA[cur];
    const u16* B_ = sB[cur];

    // ---- phase 0: quadrant (mq=0, nq=0) ----
    #pragma unroll
    for (int mi = 0; mi < 4; mi++)
      #pragma unroll
      for (int ks = 0; ks < 2; ks++) {
        int row = wm2 * 128 + mi * 16 + c;
        af[mi * 2 + ks] = *(const bf16x8*)(A_ + row * 64 + (((ks * 4 + g) ^ (row & 7)) * 8));
      }
    #pragma unroll
    for (int ni = 0; ni < 2; ni++)
      #pragma unroll
      for (int ks = 0; ks < 2; ks++) {
        int row = wn4 * 64 + ni * 16 + c;
        bf0[ni * 2 + ks] = *(const bf16x8*)(B_ + row * 64 + (((ks * 4 + g) ^ (row & 7)) * 8));
      }
    if (kt + 1 < 16) STAGE_A(1, kt + 1, (kt + 1) & 1);
    PWAIT_V(tail);
    __builtin_amdgcn_s_setprio(1);
    #pragma unroll
    for (int mi = 0; mi < 4; mi++)
      #pragma unroll
      for (int ni = 0; ni < 2; ni++)
        #pragma unroll
        for (int ks = 0; ks < 2; ks++)
          acc[mi][ni] = __builtin_amdgcn_mfma_f32_16x16x32_bf16(af[mi * 2 + ks], bf0[ni * 2 + ks], acc[mi][ni], 0, 0, 0);
    __builtin_amdgcn_s_setprio(0);

    // ---- phase 1: quadrant (mq=0, nq=1) ----
    #pragma unroll
    for (int ni = 0; ni < 2; ni++)
      #pragma unroll
      for (int ks = 0; ks < 2; ks++) {
        int row = wn4 * 64 + 32 + ni * 16 + c;
        bf1[ni * 2 + ks] = *(const bf16x8*)(B_ + row * 64 + (((ks * 4 + g) ^ (row & 7)) * 8));
      }
    if (kt + 1 < 16) STAGE_B(1, kt + 1, (kt + 1) & 1);
    PWAIT_N();
    __builtin_amdgcn_s_setprio(1);
    #pragma unroll
    for (int mi = 0; mi < 4; mi++)
      #pragma unroll
      for (int ni = 0; ni < 2; ni++)
        #pragma unroll
        for (int ks = 0; ks < 2; ks++)
          acc[mi][2 + ni] = __builtin_amdgcn_mfma_f32_16x16x32_bf16(af[mi * 2 + ks], bf1[ni * 2 + ks], acc[mi][2 + ni], 0, 0, 0);
    __builtin_amdgcn_s_setprio(0);

    // ---- phase 2: quadrant (mq=1, nq=0) ----
    #pragma unroll
    for (int mi = 0; mi < 4; mi++)
      #pragma unroll
      for (int ks = 0; ks < 2; ks++) {
        int row = wm2 * 128 + 64 + mi * 16 + c;
        af[mi * 2 + ks] = *(const bf16x8*)(A_ + row * 64 + (((ks * 4 + g) ^ (row & 7)) * 8));
      }
    if (kt + 2 < 16) STAGE_A(0, kt + 2, cur);
    PWAIT_N();
    __builtin_amdgcn_s_setprio(1);
    #pragma unroll
    for (int mi = 0; mi < 4; mi++)
      #pragma unroll
      for (int ni = 0; ni < 2; ni++)
        #pragma unroll
        for (int ks = 0; ks < 2; ks++)
          acc[4 + mi][ni] = __builtin_amdgcn_mfma_f32_16x16x32_bf16(af[mi * 2 + ks], bf0[ni * 2 + ks], acc[4 + mi][ni], 0, 0, 0);
    __builtin_amdgcn_s_setprio(0);

    // ---- phase 3: quadrant (mq=1, nq=1) ----
    if (kt + 2 < 16) STAGE_B(0, kt + 2, cur);
    PWAIT_N();
    __builtin_amdgcn_s_setprio(1);
    #pragma unroll
    for (int mi = 0; mi < 4; mi++)
      #pragma unroll
      for (int ni = 0; ni < 2; ni++)
        #pragma unroll
        for (int ks = 0; ks < 2; ks++)
          acc[4 + mi][2 + ni] = __builtin_amdgcn_mfma_f32_16x16x32_bf16(af[mi * 2 + ks], bf1[ni * 2 + ks], acc[4 + mi][2 + ni], 0, 0, 0);
    __builtin_amdgcn_s_setprio(0);
  }

  // epilogue: QKV scatter (Q scaled, K, V transposed)
  #pragma unroll
  for (int am = 0; am < 8; am++) {
    int grow0 = bm * 256 + wm2 * 128 + (am >> 2) * 64 + (am & 3) * 16 + g * 4;
    int b = grow0 >> 11, s0 = grow0 & 2047;
    #pragma unroll
    for (int an = 0; an < 4; an++) {
      int gcol = bn * 256 + wn4 * 64 + (an >> 1) * 32 + (an & 1) * 16 + c;
      int which = gcol >> 10, rem = gcol & 1023;
      int hh = rem >> 6, dd = rem & 63;
      if (which == 2) {                    // V -> transposed [B,H,Dh,S]
        u16x4 hv;
        #pragma unroll
        for (int r = 0; r < 4; r++) hv[r] = f2bf(acc[am][an][r]);
        size_t off = ((size_t)((b * 16 + hh) * 64 + dd)) * 2048 + s0;
        *(u16x4*)(Vth + off) = hv;
      } else {                             // Q or K -> [B,H,S,Dh]
        u16* dh = which ? Kh : Qh;
        float sc = which ? 1.0f : QSCALE;
        #pragma unroll
        for (int r = 0; r < 4; r++) {
          size_t off = ((size_t)(b * 16 + hh) * 2048 + (s0 + r)) * 64 + dd;
          dh[off] = f2bf(acc[am][an][r] * sc);
        }
      }
    }
  }
#undef STAGE_A
#undef STAGE_B
#undef PWAIT_V
#undef PWAIT_N
}

// ---------------- K4: out-proj GEMM (128x128, 2-stage) ----------------
__global__ __launch_bounds__(256) void k_gemmo(
    const u16* __restrict__ Ah, const u16* __restrict__ Bh,
    float* __restrict__ Cout, const float* __restrict__ bias) {
  __shared__ u16 sA[2][128 * 64];
  __shared__ u16 sB[2][128 * 64];
  const int t = threadIdx.x, lane = t & 63, w = t >> 6;
  const int bm = blockIdx.x, bn = blockIdx.y;
  const int wm = (w >> 1) * 64, wn = (w & 1) * 64;
  const int g = lane >> 4, c = lane & 15;
  const size_t arow0 = (size_t)bm * 128, brow0 = (size_t)bn * 128;

  const int r0 = t >> 3, cc0 = t & 7;
  const int cs0 = cc0 ^ (r0 & 7);
  const u16* gA = Ah + (arow0 + r0) * 1024 + cs0 * 8;
  const u16* gB = Bh + (brow0 + r0) * 1024 + cs0 * 8;

  f32x4 acc[4][4] = {};

  #pragma unroll
  for (int i = 0; i < 4; i++) {
    gl16(gA + (size_t)i * 32768, sA[0] + (size_t)(t + i * 256) * 8);
    gl16(gB + (size_t)i * 32768, sB[0] + (size_t)(t + i * 256) * 8);
  }
  gA += 64; gB += 64;
  __syncthreads();

  for (int kt = 0; kt < 16; kt++) {
    const int cur = kt & 1, nxt = cur ^ 1;
    if (kt + 1 < 16) {
      #pragma unroll
      for (int i = 0; i < 4; i++) {
        gl16(gA + (size_t)i * 32768, sA[nxt] + (size_t)(t + i * 256) * 8);
        gl16(gB + (size_t)i * 32768, sB[nxt] + (size_t)(t + i * 256) * 8);
      }
      gA += 64; gB += 64;
    }
    #pragma unroll
    for (int ks = 0; ks < 2; ks++) {
      bf16x8 afh[4], bfh[4];
      #pragma unroll
      for (int mi = 0; mi < 4; mi++) {
        int row = wm + mi * 16 + c;
        afh[mi] = *(const bf16x8*)(sA[cur] + row * 64 + (((ks * 4 + g) ^ (row & 7)) * 8));
      }
      #pragma unroll
      for (int ni = 0; ni < 4; ni++) {
        int row = wn + ni * 16 + c;
        bfh[ni] = *(const bf16x8*)(sB[cur] + row * 64 + (((ks * 4 + g) ^ (row & 7)) * 8));
      }
      #pragma unroll
      for (int mi = 0; mi < 4; mi++)
        #pragma unroll
        for (int ni = 0; ni < 4; ni++)
          acc[mi][ni] = __builtin_amdgcn_mfma_f32_16x16x32_bf16(afh[mi], bfh[ni], acc[mi][ni], 0, 0, 0);
    }
    __syncthreads();
  }

  #pragma unroll
  for (int mi = 0; mi < 4; mi++) {
    int grow0 = bm * 128 + wm + mi * 16 + g * 4;
    #pragma unroll
    for (int ni = 0; ni < 4; ni++) {
      int gcol = bn * 128 + wn + ni * 16 + c;
      float bb = bias[gcol];
      #pragma unroll
      for (int r = 0; r < 4; r++)
        Cout[(size_t)(grow0 + r) * 1024 + gcol] = acc[mi][ni][r] + bb;
    }
  }
}

// ---------------- K3: block-causal flash attention (v9, unchanged) ----------
__global__ __launch_bounds__(512, 4) void k_attn(
    const u16* __restrict__ Qh, const u16* __restrict__ Kh,
    const u16* __restrict__ Vth, u16* __restrict__ Oh) {
  __shared__ u16 lK[2][128 * 64], lV[2][64 * 128];
  const int t = threadIdx.x, lane = t & 63, w = t >> 6;
  const int bh = blockIdx.x;
  const int qt = 15 - blockIdx.y;
  const int b = bh >> 4, h = bh & 15;
  const int qrow0 = qt * 128;
  const int kvlen = (qt / 2 + 1) * 256;
  const int g = lane >> 4, c = lane & 15;

  bf16x8 qf[2];
  {
    const u16* qb = Qh + ((size_t)bh * 2048 + qrow0 + w * 16) * 64;
    #pragma unroll
    for (int ks = 0; ks < 2; ks++)
      qf[ks] = *(const bf16x8*)(qb + (size_t)c * 64 + ks * 32 + g * 8);
  }

  const u16* Kb = Kh + (size_t)bh * 2048 * 64;
  const u16* Vb = Vth + (size_t)bh * 64 * 2048;

  int kbase[2], vbase[4];
  #pragma unroll
  for (int ks = 0; ks < 2; ks++) kbase[ks] = c * 64 + (((ks * 4 + g) ^ (c & 7)) * 8);
  #pragma unroll
  for (int ks = 0; ks < 4; ks++) vbase[ks] = c * 128 + (((ks * 4 + g) ^ c) * 8);

  const int kr0 = t >> 3, kcs0 = (t & 7) ^ (kr0 & 7);
  const int vr0 = t >> 4, vcs0 = (t & 15) ^ (vr0 & 15);

  const bf16x8 vones = {(short)0x3F80, (short)0x3F80, (short)0x3F80, (short)0x3F80,
                        (short)0x3F80, (short)0x3F80, (short)0x3F80, (short)0x3F80};

  float mrun = 0.f;
  f32x4 lsum = {0.f, 0.f, 0.f, 0.f};
  f32x4 o[4] = {};

  const int ntiles = kvlen >> 7;

  gl16(Kb + (size_t)kr0 * 64 + kcs0 * 8, lK[0] + (size_t)t * 8);
  gl16(Kb + (size_t)(kr0 + 64) * 64 + kcs0 * 8, lK[0] + (size_t)(t + 512) * 8);
  gl16(Vb + (size_t)vr0 * 2048 + vcs0 * 8, lV[0] + (size_t)t * 8);
  gl16(Vb + (size_t)(vr0 + 32) * 2048 + vcs0 * 8, lV[0] + (size_t)(t + 512) * 8);
  __syncthreads();

  const u16* gK = Kb + (size_t)(128 + kr0) * 64 + kcs0 * 8;
  const u16* gV = Vb + (size_t)vr0 * 2048 + 128 + vcs0 * 8;

  for (int kt = 0; kt < ntiles; kt++) {
    const int cur = kt & 1, nxt = cur ^ 1;
    if (kt + 1 < ntiles) {
      gl16(gK, lK[nxt] + (size_t)t * 8);
      gl16(gK + 64 * 64, lK[nxt] + (size_t)(t + 512) * 8);
      gl16(gV, lV[nxt] + (size_t)t * 8);
      gl16(gV + 32 * 2048, lV[nxt] + (size_t)(t + 512) * 8);
      gK += 128 * 64;  gV += 128;
    }

    f32x4 s[8];
    #pragma unroll
    for (int ni = 0; ni < 8; ni++)
      s[ni] = (f32x4){-mrun, -mrun, -mrun, -mrun};
    __builtin_amdgcn_s_setprio(1);
    #pragma unroll
    for (int ni = 0; ni < 8; ni++)
      #pragma unroll
      for (int ks = 0; ks < 2; ks++) {
        bf16x8 kf = *(const bf16x8*)(lK[cur] + ni * 1024 + kbase[ks]);
        s[ni] = __builtin_amdgcn_mfma_f32_16x16x32_bf16(kf, qf[ks], s[ni], 0, 0, 0);
      }
    __builtin_amdgcn_s_setprio(0);

    float tl = fmaxf(fmaxf(fmaxf(fmax4(s[0]), fmax4(s[1])), fmaxf(fmax4(s[2]), fmax4(s[3]))),
                     fmaxf(fmaxf(fmax4(s[4]), fmax4(s[5])), fmaxf(fmax4(s[6]), fmax4(s[7]))));
    if (!__all(tl <= 8.0f)) {
      float tm = fmaxf(tl, __shfl_xor(tl, 16));
      tm = fmaxf(tm, __shfl_xor(tm, 32));
      float delta = fmaxf(tm, 0.0f);
      mrun += delta;
      float al = fexp2(-delta);
      #pragma unroll
      for (int ni = 0; ni < 8; ni++)
        #pragma unroll
        for (int r = 0; r < 4; r++) s[ni][r] -= delta;
      #pragma unroll
      for (int r = 0; r < 4; r++) {
        float ar = __shfl(al, g * 4 + r);
        lsum[r] *= ar;
        #pragma unroll
        for (int di = 0; di < 4; di++) o[di][r] *= ar;
      }
    }

    bf16x8 pa[4];
    #pragma unroll
    for (int ks = 0; ks < 4; ks++) {
      unsigned int e0 = cvtpk(fexp2(s[2 * ks][0]), fexp2(s[2 * ks][1]));
      unsigned int e1 = cvtpk(fexp2(s[2 * ks][2]), fexp2(s[2 * ks][3]));
      unsigned int f0 = cvtpk(fexp2(s[2 * ks + 1][0]), fexp2(s[2 * ks + 1][1]));
      unsigned int f1 = cvtpk(fexp2(s[2 * ks + 1][2]), fexp2(s[2 * ks + 1][3]));
      asm volatile("v_permlane32_swap_b32 %0, %1" : "+v"(e0), "+v"(f0));
      asm volatile("v_permlane16_swap_b32 %0, %1" : "+v"(e0), "+v"(f0));
      asm volatile("v_permlane32_swap_b32 %0, %1" : "+v"(e1), "+v"(f1));
      asm volatile("v_permlane16_swap_b32 %0, %1" : "+v"(e1), "+v"(f1));
      union { u32x4 u; bf16x8 bv; } cvu;
      cvu.u = (u32x4){e0, e1, f0, f1};
      pa[ks] = cvu.bv;
    }

    __builtin_amdgcn_s_setprio(1);
    #pragma unroll
    for (int di = 0; di < 4; di++)
      #pragma unroll
      for (int ks = 0; ks < 4; ks++) {
        bf16x8 vf = *(const bf16x8*)(lV[cur] + di * 2048 + vbase[ks]);
        o[di] = __builtin_amdgcn_mfma_f32_16x16x32_bf16(pa[ks], vf, o[di], 0, 0, 0);
      }
    #pragma unroll
    for (int ks = 0; ks < 4; ks++)
      lsum = __builtin_amdgcn_mfma_f32_16x16x32_bf16(pa[ks], vones, lsum, 0, 0, 0);
    __builtin_amdgcn_s_setprio(0);

    __syncthreads();
  }

  #pragma unroll
  for (int r = 0; r < 4; r++) {
    float ir = 1.0f / lsum[r];
    int srow = qrow0 + w * 16 + g * 4 + r;
    size_t rowo = ((size_t)b * 2048 + srow) * 1024 + h * 64;
    #pragma unroll
    for (int di = 0; di < 4; di++)
      Oh[rowo + di * 16 + c] = f2bf(o[di][r] * ir);
  }
}

// ---------------- launch ----------------
extern "C" void kernel_launch(void* const* d_in, const int* in_sizes, int n_in,
                              void* d_out, int out_size, void* d_ws, size_t ws_size,
                              hipStream_t stream) {
  const float* x     = (const float*)d_in[0];
  const float* gamma = (const float*)d_in[1];
  const float* beta  = (const float*)d_in[2];
  const float* Wqkv  = (const float*)d_in[3];
  const float* Wout  = (const float*)d_in[4];
  const float* bout  = (const float*)d_in[5];
  float* out = (float*)d_out;

  char* ws = (char*)d_ws;
  size_t off = 0;
  auto alloc = [&](size_t bytes) { char* p = ws + off; off += (bytes + 255) & ~(size_t)255; return p; };
  const size_t SZ_XN = (size_t)8192 * 1024 * 2;
  const size_t SZ_WQ = (size_t)3072 * 1024 * 2;
  const size_t SZ_WO = (size_t)1024 * 1024 * 2;
  const size_t SZ_QKV = (size_t)4 * 16 * 2048 * 64 * 2;
  u16* xnh  = (u16*)alloc(SZ_XN);   // also attnout (bf16) after attention
  u16* wqth = (u16*)alloc(SZ_WQ);
  u16* woth = (u16*)alloc(SZ_WO);
  u16* Qh  = (u16*)alloc(SZ_QKV);
  u16* Kh  = (u16*)alloc(SZ_QKV);
  u16* Vth = (u16*)alloc(SZ_QKV);
  if (off > ws_size) return;

  k_ln_split<<<8192, 256, 0, stream>>>(x, gamma, beta, xnh);
  k_wsplit_t<<<dim3(96, 32), 256, 0, stream>>>(Wqkv, wqth, 1024, 3072);
  k_wsplit_t<<<dim3(32, 32), 256, 0, stream>>>(Wout, woth, 1024, 1024);
  // QKV projection: 256x256-tile 4-phase counted-vmcnt GEMM
  k_gemmq<<<dim3(32, 12), 512, 0, stream>>>(xnh, wqth, Qh, Kh, Vth);
  // attnout (bf16) reuses the xn buffer (xn is dead after the QKV GEMM)
  k_attn<<<dim3(64, 16), 512, 0, stream>>>(Qh, Kh, Vth, xnh);
  k_gemmo<<<dim3(64, 8), 256, 0, stream>>>(xnh, woth, out, bout);
}

// Round 15
// 155.878 us; speedup vs baseline: 1.0518x; 1.0163x over previous
//
#include <hip/hip_runtime.h>
#include <stdint.h>

typedef unsigned short u16;
typedef __attribute__((ext_vector_type(8))) short bf16x8;
typedef __attribute__((ext_vector_type(4))) float f32x4;
typedef __attribute__((ext_vector_type(4))) unsigned short u16x4;
typedef __attribute__((ext_vector_type(4))) unsigned int u32x4;

#define DEVI static __device__ __forceinline__

// dots*scale folded into Q, with base-2 softmax: exp(s) == exp2(s*log2e)
#define QSCALE (0.125f * 1.4426950408889634f)

DEVI u16 f2bf(float f) {
  union { float f; unsigned int u; } v; v.f = f;
  unsigned int u = v.u + 0x7fffu + ((v.u >> 16) & 1u);
  return (u16)(u >> 16);
}
DEVI void gl16(const void* g, void* l) {
  __builtin_amdgcn_global_load_lds(
      (__attribute__((address_space(1))) void*)g,
      (__attribute__((address_space(3))) void*)l, 16, 0, 0);
}
// packed f32x2 -> bf16x2 (RNE), lo=bf16(a), hi=bf16(b)
DEVI unsigned int cvtpk(float a, float b) {
  unsigned int r;
  asm("v_cvt_pk_bf16_f32 %0, %1, %2" : "=v"(r) : "v"(a), "v"(b));
  return r;
}
// raw v_exp_f32 (flushes f32 denormal results -- fine here)
DEVI float fexp2(float x) {
  float r;
  asm("v_exp_f32 %0, %1\n\ts_nop 0" : "=v"(r) : "v"(x));
  return r;
}
DEVI float fmax4(f32x4 v) {
  return fmaxf(fmaxf(v[0], v[1]), fmaxf(v[2], v[3]));
}

// ---------------- K1: LayerNorm -> bf16 ----------------
__global__ __launch_bounds__(256) void k_ln_split(
    const float* __restrict__ x, const float* __restrict__ gamma,
    const float* __restrict__ beta, u16* __restrict__ xh) {
  const int row = blockIdx.x;
  const int t = threadIdx.x;
  const float4* xr = (const float4*)(x + (size_t)row * 1024);
  float4 v = xr[t];
  float s = v.x + v.y + v.z + v.w;
  float s2 = v.x * v.x + v.y * v.y + v.z * v.z + v.w * v.w;
  #pragma unroll
  for (int m = 1; m < 64; m <<= 1) { s += __shfl_xor(s, m); s2 += __shfl_xor(s2, m); }
  __shared__ float ls[4], ls2[4];
  if ((t & 63) == 0) { ls[t >> 6] = s; ls2[t >> 6] = s2; }
  __syncthreads();
  s = ls[0] + ls[1] + ls[2] + ls[3];
  s2 = ls2[0] + ls2[1] + ls2[2] + ls2[3];
  float mu = s * (1.0f / 1024.0f);
  float var = s2 * (1.0f / 1024.0f) - mu * mu;
  float rstd = rsqrtf(var + 1e-5f);
  float4 g = ((const float4*)gamma)[t];
  float4 b = ((const float4*)beta)[t];
  float xv[4] = {v.x, v.y, v.z, v.w};
  float gg[4] = {g.x, g.y, g.z, g.w};
  float bb[4] = {b.x, b.y, b.z, b.w};
  u16x4 hv;
  #pragma unroll
  for (int i = 0; i < 4; i++) {
    float xn = (xv[i] - mu) * rstd * gg[i] + bb[i];
    hv[i] = f2bf(xn);
  }
  ((u16x4*)xh)[(size_t)row * 256 + t] = hv;
}

// ---------------- K1b: transpose weights, fp32 -> bf16 ----------------
__global__ __launch_bounds__(256) void k_wsplit_t(
    const float* __restrict__ W, u16* __restrict__ Wth, int K, int N) {
  __shared__ float tile[32][33];
  const int t = threadIdx.x;
  const int tx = t & 31, ty = t >> 5;
  #pragma unroll
  for (int i = 0; i < 4; i++) {
    int k = blockIdx.y * 32 + ty + i * 8;
    int n = blockIdx.x * 32 + tx;
    tile[ty + i * 8][tx] = W[(size_t)k * N + n];
  }
  __syncthreads();
  #pragma unroll
  for (int i = 0; i < 4; i++) {
    int n = blockIdx.x * 32 + ty + i * 8;
    int k = blockIdx.y * 32 + tx;
    Wth[(size_t)n * K + k] = f2bf(tile[tx][ty + i * 8]);
  }
}

// ---------------- K2: Q,K GEMM, 256x256 tile, 4-phase, counted vmcnt ------
// N=2048 (Q,K cols only) -> grid 32x8 = 256 blocks = EXACTLY one round at
// 1 block/CU (128KB LDS). No idle second round (the R13/R14 quantization).
__global__ __launch_bounds__(512, 2) void k_gemmq(
    const u16* __restrict__ Ah, const u16* __restrict__ Bh,
    u16* __restrict__ Qh, u16* __restrict__ Kh) {
  __shared__ u16 sA[2][256 * 64];
  __shared__ u16 sB[2][256 * 64];
  const int t = threadIdx.x, lane = t & 63, w = t >> 6;
  const int bm = blockIdx.x, bn = blockIdx.y;
  const int wm2 = w >> 2, wn4 = w & 3;      // 2 M-waves x 4 N-waves
  const int g = lane >> 4, c = lane & 15;
  const size_t arow0 = (size_t)bm * 256, brow0 = (size_t)bn * 256;

  const int sr = t >> 3;
  const int scs = (t & 7) ^ (sr & 7);
  const int brs = (t >> 3) & 31;
  const int bcs = (t & 7) ^ (brs & 7);
  const int bsj = t >> 8;

  f32x4 acc[8][4] = {};

#define STAGE_A(u, kt, b) do { \
    int rA0 = (u) * 64 + sr, rA1 = 128 + rA0; \
    gl16(Ah + (arow0 + rA0) * 1024 + (size_t)(kt) * 64 + scs * 8, \
         sA[b] + (size_t)((u) * 512 + t) * 8); \
    gl16(Ah + (arow0 + rA1) * 1024 + (size_t)(kt) * 64 + scs * 8, \
         sA[b] + (size_t)(1024 + (u) * 512 + t) * 8); \
  } while (0)
#define STAGE_B(u, kt, b) do { \
    int s0_ = bsj, s1_ = bsj + 2; \
    int rB0 = (u) * 32 + s0_ * 64 + brs, rB1 = (u) * 32 + s1_ * 64 + brs; \
    gl16(Bh + (brow0 + rB0) * 1024 + (size_t)(kt) * 64 + bcs * 8, \
         sB[b] + (size_t)(rB0 * 8 + (t & 7)) * 8); \
    gl16(Bh + (brow0 + rB1) * 1024 + (size_t)(kt) * 64 + bcs * 8, \
         sB[b] + (size_t)(rB1 * 8 + (t & 7)) * 8); \
  } while (0)
#define PWAIT_V(tail) do { \
    if (tail) asm volatile("s_waitcnt vmcnt(0)" ::: "memory"); \
    else      asm volatile("s_waitcnt vmcnt(6)" ::: "memory"); \
    __builtin_amdgcn_s_barrier(); \
    asm volatile("s_waitcnt lgkmcnt(0)" ::: "memory"); \
  } while (0)
#define PWAIT_N() do { \
    __builtin_amdgcn_s_barrier(); \
    asm volatile("s_waitcnt lgkmcnt(0)" ::: "memory"); \
  } while (0)

  STAGE_A(0, 0, 0); STAGE_B(0, 0, 0);
  STAGE_A(1, 0, 0); STAGE_B(1, 0, 0);
  STAGE_A(0, 1, 1); STAGE_B(0, 1, 1);
  PWAIT_V(0);

  bf16x8 af[8], bf0[4], bf1[4];
  for (int kt = 0; kt < 16; kt++) {
    const int cur = kt & 1;
    const int tail = (kt >= 14);
    const u16* A_ = sA[cur];
    const u16* B_ = sB[cur];

    // ---- phase 0: quadrant (mq=0, nq=0) ----
    #pragma unroll
    for (int mi = 0; mi < 4; mi++)
      #pragma unroll
      for (int ks = 0; ks < 2; ks++) {
        int row = wm2 * 128 + mi * 16 + c;
        af[mi * 2 + ks] = *(const bf16x8*)(A_ + row * 64 + (((ks * 4 + g) ^ (row & 7)) * 8));
      }
    #pragma unroll
    for (int ni = 0; ni < 2; ni++)
      #pragma unroll
      for (int ks = 0; ks < 2; ks++) {
        int row = wn4 * 64 + ni * 16 + c;
        bf0[ni * 2 + ks] = *(const bf16x8*)(B_ + row * 64 + (((ks * 4 + g) ^ (row & 7)) * 8));
      }
    if (kt + 1 < 16) STAGE_A(1, kt + 1, (kt + 1) & 1);
    PWAIT_V(tail);
    __builtin_amdgcn_s_setprio(1);
    #pragma unroll
    for (int mi = 0; mi < 4; mi++)
      #pragma unroll
      for (int ni = 0; ni < 2; ni++)
        #pragma unroll
        for (int ks = 0; ks < 2; ks++)
          acc[mi][ni] = __builtin_amdgcn_mfma_f32_16x16x32_bf16(af[mi * 2 + ks], bf0[ni * 2 + ks], acc[mi][ni], 0, 0, 0);
    __builtin_amdgcn_s_setprio(0);

    // ---- phase 1: quadrant (mq=0, nq=1) ----
    #pragma unroll
    for (int ni = 0; ni < 2; ni++)
      #pragma unroll
      for (int ks = 0; ks < 2; ks++) {
        int row = wn4 * 64 + 32 + ni * 16 + c;
        bf1[ni * 2 + ks] = *(const bf16x8*)(B_ + row * 64 + (((ks * 4 + g) ^ (row & 7)) * 8));
      }
    if (kt + 1 < 16) STAGE_B(1, kt + 1, (kt + 1) & 1);
    PWAIT_N();
    __builtin_amdgcn_s_setprio(1);
    #pragma unroll
    for (int mi = 0; mi < 4; mi++)
      #pragma unroll
      for (int ni = 0; ni < 2; ni++)
        #pragma unroll
        for (int ks = 0; ks < 2; ks++)
          acc[mi][2 + ni] = __builtin_amdgcn_mfma_f32_16x16x32_bf16(af[mi * 2 + ks], bf1[ni * 2 + ks], acc[mi][2 + ni], 0, 0, 0);
    __builtin_amdgcn_s_setprio(0);

    // ---- phase 2: quadrant (mq=1, nq=0) ----
    #pragma unroll
    for (int mi = 0; mi < 4; mi++)
      #pragma unroll
      for (int ks = 0; ks < 2; ks++) {
        int row = wm2 * 128 + 64 + mi * 16 + c;
        af[mi * 2 + ks] = *(const bf16x8*)(A_ + row * 64 + (((ks * 4 + g) ^ (row & 7)) * 8));
      }
    if (kt + 2 < 16) STAGE_A(0, kt + 2, cur);
    PWAIT_N();
    __builtin_amdgcn_s_setprio(1);
    #pragma unroll
    for (int mi = 0; mi < 4; mi++)
      #pragma unroll
      for (int ni = 0; ni < 2; ni++)
        #pragma unroll
        for (int ks = 0; ks < 2; ks++)
          acc[4 + mi][ni] = __builtin_amdgcn_mfma_f32_16x16x32_bf16(af[mi * 2 + ks], bf0[ni * 2 + ks], acc[4 + mi][ni], 0, 0, 0);
    __builtin_amdgcn_s_setprio(0);

    // ---- phase 3: quadrant (mq=1, nq=1) ----
    if (kt + 2 < 16) STAGE_B(0, kt + 2, cur);
    PWAIT_N();
    __builtin_amdgcn_s_setprio(1);
    #pragma unroll
    for (int mi = 0; mi < 4; mi++)
      #pragma unroll
      for (int ni = 0; ni < 2; ni++)
        #pragma unroll
        for (int ks = 0; ks < 2; ks++)
          acc[4 + mi][2 + ni] = __builtin_amdgcn_mfma_f32_16x16x32_bf16(af[mi * 2 + ks], bf1[ni * 2 + ks], acc[4 + mi][2 + ni], 0, 0, 0);
    __builtin_amdgcn_s_setprio(0);
  }

  // epilogue: Q,K scatter (gcol < 2048 by construction)
  #pragma unroll
  for (int am = 0; am < 8; am++) {
    int grow0 = bm * 256 + wm2 * 128 + (am >> 2) * 64 + (am & 3) * 16 + g * 4;
    int b = grow0 >> 11, s0 = grow0 & 2047;
    #pragma unroll
    for (int an = 0; an < 4; an++) {
      int gcol = bn * 256 + wn4 * 64 + (an >> 1) * 32 + (an & 1) * 16 + c;
      int which = gcol >> 10, rem = gcol & 1023;
      int hh = rem >> 6, dd = rem & 63;
      u16* dh = which ? Kh : Qh;
      float sc = which ? 1.0f : QSCALE;
      #pragma unroll
      for (int r = 0; r < 4; r++) {
        size_t off = ((size_t)(b * 16 + hh) * 2048 + (s0 + r)) * 64 + dd;
        dh[off] = f2bf(acc[am][an][r] * sc);
      }
    }
  }
#undef STAGE_A
#undef STAGE_B
#undef PWAIT_V
#undef PWAIT_N
}

// ---------------- K2b/K4: 128x128 single-buffer GEMM (wave-overlap regime) --
// 256 threads, BK=64, 32KB LDS single-buffered, 2-barrier loop. VGPR ~112 ->
// 4 blocks/CU (16 waves/CU): cross-block wave overlap hides the barrier drain
// (m97/m114 mechanism). Grid 64x8 = 512 blocks = all resident, no rounds.
// MODE 2: V epilogue (transposed bf16 scatter). MODE 1: out-proj (+bias fp32).
template <int MODE>
__global__ __launch_bounds__(256) void k_gemm2(
    const u16* __restrict__ Ah, const u16* __restrict__ Bh,
    u16* __restrict__ Vth, float* __restrict__ Cout,
    const float* __restrict__ bias) {
  __shared__ u16 sA[128 * 64];
  __shared__ u16 sB[128 * 64];
  const int t = threadIdx.x, lane = t & 63, w = t >> 6;
  const int bm = blockIdx.x, bn = blockIdx.y;
  const int wm = (w >> 1) * 64, wn = (w & 1) * 64;
  const int g = lane >> 4, c = lane & 15;
  const size_t arow0 = (size_t)bm * 128, brow0 = (size_t)bn * 128;

  f32x4 acc[4][4] = {};

  for (int kt = 0; kt < 16; kt++) {
    __syncthreads();
    #pragma unroll
    for (int i = 0; i < 4; i++) {
      int ci = t + i * 256;              // 1024 chunks of 16B per operand tile
      int r = ci >> 3, cc = ci & 7;
      int cs = cc ^ (r & 7);
      size_t ka = (size_t)kt * 64 + cs * 8;
      gl16(Ah + (arow0 + r) * 1024 + ka, sA + (size_t)ci * 8);
      gl16(Bh + (brow0 + r) * 1024 + ka, sB + (size_t)ci * 8);
    }
    __syncthreads();
    #pragma unroll
    for (int ks = 0; ks < 2; ks++) {
      bf16x8 afh[4], bfh[4];
      #pragma unroll
      for (int mi = 0; mi < 4; mi++) {
        int row = wm + mi * 16 + c;
        afh[mi] = *(const bf16x8*)(sA + row * 64 + (((ks * 4 + g) ^ (row & 7)) * 8));
      }
      #pragma unroll
      for (int ni = 0; ni < 4; ni++) {
        int row = wn + ni * 16 + c;
        bfh[ni] = *(const bf16x8*)(sB + row * 64 + (((ks * 4 + g) ^ (row & 7)) * 8));
      }
      #pragma unroll
      for (int mi = 0; mi < 4; mi++)
        #pragma unroll
        for (int ni = 0; ni < 4; ni++)
          acc[mi][ni] = __builtin_amdgcn_mfma_f32_16x16x32_bf16(afh[mi], bfh[ni], acc[mi][ni], 0, 0, 0);
    }
  }

  if (MODE == 2) {                       // V -> transposed [B,H,Dh,S]
    #pragma unroll
    for (int mi = 0; mi < 4; mi++) {
      int grow0 = bm * 128 + wm + mi * 16 + g * 4;   // m = b*2048+s
      int b = grow0 >> 11, s0 = grow0 & 2047;
      #pragma unroll
      for (int ni = 0; ni < 4; ni++) {
        int vcol = bn * 128 + wn + ni * 16 + c;       // 0..1023
        int hh = vcol >> 6, dd = vcol & 63;
        u16x4 hv;
        #pragma unroll
        for (int r = 0; r < 4; r++) hv[r] = f2bf(acc[mi][ni][r]);
        size_t off = ((size_t)((b * 16 + hh) * 64 + dd)) * 2048 + s0;
        *(u16x4*)(Vth + off) = hv;
      }
    }
  } else {                               // out-proj: +bias, fp32
    #pragma unroll
    for (int mi = 0; mi < 4; mi++) {
      int grow0 = bm * 128 + wm + mi * 16 + g * 4;
      #pragma unroll
      for (int ni = 0; ni < 4; ni++) {
        int gcol = bn * 128 + wn + ni * 16 + c;
        float bb = bias[gcol];
        #pragma unroll
        for (int r = 0; r < 4; r++)
          Cout[(size_t)(grow0 + r) * 1024 + gcol] = acc[mi][ni][r] + bb;
      }
    }
  }
}

// ---------------- K3: block-causal flash attention (v9, unchanged) ----------
__global__ __launch_bounds__(512, 4) void k_attn(
    const u16* __restrict__ Qh, const u16* __restrict__ Kh,
    const u16* __restrict__ Vth, u16* __restrict__ Oh) {
  __shared__ u16 lK[2][128 * 64], lV[2][64 * 128];
  const int t = threadIdx.x, lane = t & 63, w = t >> 6;
  const int bh = blockIdx.x;
  const int qt = 15 - blockIdx.y;
  const int b = bh >> 4, h = bh & 15;
  const int qrow0 = qt * 128;
  const int kvlen = (qt / 2 + 1) * 256;
  const int g = lane >> 4, c = lane & 15;

  bf16x8 qf[2];
  {
    const u16* qb = Qh + ((size_t)bh * 2048 + qrow0 + w * 16) * 64;
    #pragma unroll
    for (int ks = 0; ks < 2; ks++)
      qf[ks] = *(const bf16x8*)(qb + (size_t)c * 64 + ks * 32 + g * 8);
  }

  const u16* Kb = Kh + (size_t)bh * 2048 * 64;
  const u16* Vb = Vth + (size_t)bh * 64 * 2048;

  int kbase[2], vbase[4];
  #pragma unroll
  for (int ks = 0; ks < 2; ks++) kbase[ks] = c * 64 + (((ks * 4 + g) ^ (c & 7)) * 8);
  #pragma unroll
  for (int ks = 0; ks < 4; ks++) vbase[ks] = c * 128 + (((ks * 4 + g) ^ c) * 8);

  const int kr0 = t >> 3, kcs0 = (t & 7) ^ (kr0 & 7);
  const int vr0 = t >> 4, vcs0 = (t & 15) ^ (vr0 & 15);

  const bf16x8 vones = {(short)0x3F80, (short)0x3F80, (short)0x3F80, (short)0x3F80,
                        (short)0x3F80, (short)0x3F80, (short)0x3F80, (short)0x3F80};

  float mrun = 0.f;
  f32x4 lsum = {0.f, 0.f, 0.f, 0.f};
  f32x4 o[4] = {};

  const int ntiles = kvlen >> 7;

  gl16(Kb + (size_t)kr0 * 64 + kcs0 * 8, lK[0] + (size_t)t * 8);
  gl16(Kb + (size_t)(kr0 + 64) * 64 + kcs0 * 8, lK[0] + (size_t)(t + 512) * 8);
  gl16(Vb + (size_t)vr0 * 2048 + vcs0 * 8, lV[0] + (size_t)t * 8);
  gl16(Vb + (size_t)(vr0 + 32) * 2048 + vcs0 * 8, lV[0] + (size_t)(t + 512) * 8);
  __syncthreads();

  const u16* gK = Kb + (size_t)(128 + kr0) * 64 + kcs0 * 8;
  const u16* gV = Vb + (size_t)vr0 * 2048 + 128 + vcs0 * 8;

  for (int kt = 0; kt < ntiles; kt++) {
    const int cur = kt & 1, nxt = cur ^ 1;
    if (kt + 1 < ntiles) {
      gl16(gK, lK[nxt] + (size_t)t * 8);
      gl16(gK + 64 * 64, lK[nxt] + (size_t)(t + 512) * 8);
      gl16(gV, lV[nxt] + (size_t)t * 8);
      gl16(gV + 32 * 2048, lV[nxt] + (size_t)(t + 512) * 8);
      gK += 128 * 64;  gV += 128;
    }

    f32x4 s[8];
    #pragma unroll
    for (int ni = 0; ni < 8; ni++)
      s[ni] = (f32x4){-mrun, -mrun, -mrun, -mrun};
    __builtin_amdgcn_s_setprio(1);
    #pragma unroll
    for (int ni = 0; ni < 8; ni++)
      #pragma unroll
      for (int ks = 0; ks < 2; ks++) {
        bf16x8 kf = *(const bf16x8*)(lK[cur] + ni * 1024 + kbase[ks]);
        s[ni] = __builtin_amdgcn_mfma_f32_16x16x32_bf16(kf, qf[ks], s[ni], 0, 0, 0);
      }
    __builtin_amdgcn_s_setprio(0);

    float tl = fmaxf(fmaxf(fmaxf(fmax4(s[0]), fmax4(s[1])), fmaxf(fmax4(s[2]), fmax4(s[3]))),
                     fmaxf(fmaxf(fmax4(s[4]), fmax4(s[5])), fmaxf(fmax4(s[6]), fmax4(s[7]))));
    if (!__all(tl <= 8.0f)) {
      float tm = fmaxf(tl, __shfl_xor(tl, 16));
      tm = fmaxf(tm, __shfl_xor(tm, 32));
      float delta = fmaxf(tm, 0.0f);
      mrun += delta;
      float al = fexp2(-delta);
      #pragma unroll
      for (int ni = 0; ni < 8; ni++)
        #pragma unroll
        for (int r = 0; r < 4; r++) s[ni][r] -= delta;
      #pragma unroll
      for (int r = 0; r < 4; r++) {
        float ar = __shfl(al, g * 4 + r);
        lsum[r] *= ar;
        #pragma unroll
        for (int di = 0; di < 4; di++) o[di][r] *= ar;
      }
    }

    bf16x8 pa[4];
    #pragma unroll
    for (int ks = 0; ks < 4; ks++) {
      unsigned int e0 = cvtpk(fexp2(s[2 * ks][0]), fexp2(s[2 * ks][1]));
      unsigned int e1 = cvtpk(fexp2(s[2 * ks][2]), fexp2(s[2 * ks][3]));
      unsigned int f0 = cvtpk(fexp2(s[2 * ks + 1][0]), fexp2(s[2 * ks + 1][1]));
      unsigned int f1 = cvtpk(fexp2(s[2 * ks + 1][2]), fexp2(s[2 * ks + 1][3]));
      asm volatile("v_permlane32_swap_b32 %0, %1" : "+v"(e0), "+v"(f0));
      asm volatile("v_permlane16_swap_b32 %0, %1" : "+v"(e0), "+v"(f0));
      asm volatile("v_permlane32_swap_b32 %0, %1" : "+v"(e1), "+v"(f1));
      asm volatile("v_permlane16_swap_b32 %0, %1" : "+v"(e1), "+v"(f1));
      union { u32x4 u; bf16x8 bv; } cvu;
      cvu.u = (u32x4){e0, e1, f0, f1};
      pa[ks] = cvu.bv;
    }

    __builtin_amdgcn_s_setprio(1);
    #pragma unroll
    for (int di = 0; di < 4; di++)
      #pragma unroll
      for (int ks = 0; ks < 4; ks++) {
        bf16x8 vf = *(const bf16x8*)(lV[cur] + di * 2048 + vbase[ks]);
        o[di] = __builtin_amdgcn_mfma_f32_16x16x32_bf16(pa[ks], vf, o[di], 0, 0, 0);
      }
    #pragma unroll
    for (int ks = 0; ks < 4; ks++)
      lsum = __builtin_amdgcn_mfma_f32_16x16x32_bf16(pa[ks], vones, lsum, 0, 0, 0);
    __builtin_amdgcn_s_setprio(0);

    __syncthreads();
  }

  #pragma unroll
  for (int r = 0; r < 4; r++) {
    float ir = 1.0f / lsum[r];
    int srow = qrow0 + w * 16 + g * 4 + r;
    size_t rowo = ((size_t)b * 2048 + srow) * 1024 + h * 64;
    #pragma unroll
    for (int di = 0; di < 4; di++)
      Oh[rowo + di * 16 + c] = f2bf(o[di][r] * ir);
  }
}

// ---------------- launch ----------------
extern "C" void kernel_launch(void* const* d_in, const int* in_sizes, int n_in,
                              void* d_out, int out_size, void* d_ws, size_t ws_size,
                              hipStream_t stream) {
  const float* x     = (const float*)d_in[0];
  const float* gamma = (const float*)d_in[1];
  const float* beta  = (const float*)d_in[2];
  const float* Wqkv  = (const float*)d_in[3];
  const float* Wout  = (const float*)d_in[4];
  const float* bout  = (const float*)d_in[5];
  float* out = (float*)d_out;

  char* ws = (char*)d_ws;
  size_t off = 0;
  auto alloc = [&](size_t bytes) { char* p = ws + off; off += (bytes + 255) & ~(size_t)255; return p; };
  const size_t SZ_XN = (size_t)8192 * 1024 * 2;
  const size_t SZ_WQ = (size_t)3072 * 1024 * 2;
  const size_t SZ_WO = (size_t)1024 * 1024 * 2;
  const size_t SZ_QKV = (size_t)4 * 16 * 2048 * 64 * 2;
  u16* xnh  = (u16*)alloc(SZ_XN);   // also attnout (bf16) after attention
  u16* wqth = (u16*)alloc(SZ_WQ);
  u16* woth = (u16*)alloc(SZ_WO);
  u16* Qh  = (u16*)alloc(SZ_QKV);
  u16* Kh  = (u16*)alloc(SZ_QKV);
  u16* Vth = (u16*)alloc(SZ_QKV);
  if (off > ws_size) return;

  k_ln_split<<<8192, 256, 0, stream>>>(x, gamma, beta, xnh);
  k_wsplit_t<<<dim3(96, 32), 256, 0, stream>>>(Wqkv, wqth, 1024, 3072);
  k_wsplit_t<<<dim3(32, 32), 256, 0, stream>>>(Wout, woth, 1024, 1024);
  // Q,K projection: 256 blocks = exactly one clean round at 1 block/CU
  k_gemmq<<<dim3(32, 8), 512, 0, stream>>>(xnh, wqth, Qh, Kh);
  // V projection: 512 blocks all-resident at 4 blocks/CU (wave-overlap regime)
  k_gemm2<2><<<dim3(64, 8), 256, 0, stream>>>(xnh, wqth + (size_t)2048 * 1024,
                                              Vth, nullptr, nullptr);
  // attnout (bf16) reuses the xn buffer (xn is dead after the QKV GEMMs)
  k_attn<<<dim3(64, 16), 512, 0, stream>>>(Qh, Kh, Vth, xnh);
  k_gemm2<1><<<dim3(64, 8), 256, 0, stream>>>(xnh, woth,
                                              nullptr, out, bout);
}

// Round 16
// 155.301 us; speedup vs baseline: 1.0557x; 1.0037x over previous
//
#include <hip/hip_runtime.h>
#include <stdint.h>

typedef unsigned short u16;
typedef __attribute__((ext_vector_type(8))) short bf16x8;
typedef __attribute__((ext_vector_type(4))) float f32x4;
typedef __attribute__((ext_vector_type(4))) unsigned short u16x4;
typedef __attribute__((ext_vector_type(4))) unsigned int u32x4;

#define DEVI static __device__ __forceinline__

// dots*scale folded into Q, with base-2 softmax: exp(s) == exp2(s*log2e)
#define QSCALE (0.125f * 1.4426950408889634f)

DEVI u16 f2bf(float f) {
  union { float f; unsigned int u; } v; v.f = f;
  unsigned int u = v.u + 0x7fffu + ((v.u >> 16) & 1u);
  return (u16)(u >> 16);
}
DEVI void gl16(const void* g, void* l) {
  __builtin_amdgcn_global_load_lds(
      (__attribute__((address_space(1))) void*)g,
      (__attribute__((address_space(3))) void*)l, 16, 0, 0);
}
// packed f32x2 -> bf16x2 (RNE), lo=bf16(a), hi=bf16(b)
DEVI unsigned int cvtpk(float a, float b) {
  unsigned int r;
  asm("v_cvt_pk_bf16_f32 %0, %1, %2" : "=v"(r) : "v"(a), "v"(b));
  return r;
}
// raw v_exp_f32 (flushes f32 denormal results -- fine here)
DEVI float fexp2(float x) {
  float r;
  asm("v_exp_f32 %0, %1\n\ts_nop 0" : "=v"(r) : "v"(x));
  return r;
}
DEVI float fmax4(f32x4 v) {
  return fmaxf(fmaxf(v[0], v[1]), fmaxf(v[2], v[3]));
}

// ---------------- K1: LayerNorm -> bf16 ----------------
__global__ __launch_bounds__(256) void k_ln_split(
    const float* __restrict__ x, const float* __restrict__ gamma,
    const float* __restrict__ beta, u16* __restrict__ xh) {
  const int row = blockIdx.x;
  const int t = threadIdx.x;
  const float4* xr = (const float4*)(x + (size_t)row * 1024);
  float4 v = xr[t];
  float s = v.x + v.y + v.z + v.w;
  float s2 = v.x * v.x + v.y * v.y + v.z * v.z + v.w * v.w;
  #pragma unroll
  for (int m = 1; m < 64; m <<= 1) { s += __shfl_xor(s, m); s2 += __shfl_xor(s2, m); }
  __shared__ float ls[4], ls2[4];
  if ((t & 63) == 0) { ls[t >> 6] = s; ls2[t >> 6] = s2; }
  __syncthreads();
  s = ls[0] + ls[1] + ls[2] + ls[3];
  s2 = ls2[0] + ls2[1] + ls2[2] + ls2[3];
  float mu = s * (1.0f / 1024.0f);
  float var = s2 * (1.0f / 1024.0f) - mu * mu;
  float rstd = rsqrtf(var + 1e-5f);
  float4 g = ((const float4*)gamma)[t];
  float4 b = ((const float4*)beta)[t];
  float xv[4] = {v.x, v.y, v.z, v.w};
  float gg[4] = {g.x, g.y, g.z, g.w};
  float bb[4] = {b.x, b.y, b.z, b.w};
  u16x4 hv;
  #pragma unroll
  for (int i = 0; i < 4; i++) {
    float xn = (xv[i] - mu) * rstd * gg[i] + bb[i];
    hv[i] = f2bf(xn);
  }
  ((u16x4*)xh)[(size_t)row * 256 + t] = hv;
}

// ---------------- K1b: transpose weights, fp32 -> bf16 ----------------
__global__ __launch_bounds__(256) void k_wsplit_t(
    const float* __restrict__ W, u16* __restrict__ Wth, int K, int N) {
  __shared__ float tile[32][33];
  const int t = threadIdx.x;
  const int tx = t & 31, ty = t >> 5;
  #pragma unroll
  for (int i = 0; i < 4; i++) {
    int k = blockIdx.y * 32 + ty + i * 8;
    int n = blockIdx.x * 32 + tx;
    tile[ty + i * 8][tx] = W[(size_t)k * N + n];
  }
  __syncthreads();
  #pragma unroll
  for (int i = 0; i < 4; i++) {
    int n = blockIdx.x * 32 + ty + i * 8;
    int k = blockIdx.y * 32 + tx;
    Wth[(size_t)n * K + k] = f2bf(tile[tx][ty + i * 8]);
  }
}

// ---------------- K2: Q,K GEMM, 256x256 tile, 4-phase, counted vmcnt ------
// N=2048 (Q,K cols only) -> grid 32x8 = 256 blocks = EXACTLY one round at
// 1 block/CU (128KB LDS). No idle second round.
__global__ __launch_bounds__(512, 2) void k_gemmq(
    const u16* __restrict__ Ah, const u16* __restrict__ Bh,
    u16* __restrict__ Qh, u16* __restrict__ Kh) {
  __shared__ u16 sA[2][256 * 64];
  __shared__ u16 sB[2][256 * 64];
  const int t = threadIdx.x, lane = t & 63, w = t >> 6;
  const int bm = blockIdx.x, bn = blockIdx.y;
  const int wm2 = w >> 2, wn4 = w & 3;      // 2 M-waves x 4 N-waves
  const int g = lane >> 4, c = lane & 15;
  const size_t arow0 = (size_t)bm * 256, brow0 = (size_t)bn * 256;

  const int sr = t >> 3;
  const int scs = (t & 7) ^ (sr & 7);
  const int brs = (t >> 3) & 31;
  const int bcs = (t & 7) ^ (brs & 7);
  const int bsj = t >> 8;

  f32x4 acc[8][4] = {};

#define STAGE_A(u, kt, b) do { \
    int rA0 = (u) * 64 + sr, rA1 = 128 + rA0; \
    gl16(Ah + (arow0 + rA0) * 1024 + (size_t)(kt) * 64 + scs * 8, \
         sA[b] + (size_t)((u) * 512 + t) * 8); \
    gl16(Ah + (arow0 + rA1) * 1024 + (size_t)(kt) * 64 + scs * 8, \
         sA[b] + (size_t)(1024 + (u) * 512 + t) * 8); \
  } while (0)
#define STAGE_B(u, kt, b) do { \
    int s0_ = bsj, s1_ = bsj + 2; \
    int rB0 = (u) * 32 + s0_ * 64 + brs, rB1 = (u) * 32 + s1_ * 64 + brs; \
    gl16(Bh + (brow0 + rB0) * 1024 + (size_t)(kt) * 64 + bcs * 8, \
         sB[b] + (size_t)(rB0 * 8 + (t & 7)) * 8); \
    gl16(Bh + (brow0 + rB1) * 1024 + (size_t)(kt) * 64 + bcs * 8, \
         sB[b] + (size_t)(rB1 * 8 + (t & 7)) * 8); \
  } while (0)
#define PWAIT_V(tail) do { \
    if (tail) asm volatile("s_waitcnt vmcnt(0)" ::: "memory"); \
    else      asm volatile("s_waitcnt vmcnt(6)" ::: "memory"); \
    __builtin_amdgcn_s_barrier(); \
    asm volatile("s_waitcnt lgkmcnt(0)" ::: "memory"); \
  } while (0)
#define PWAIT_N() do { \
    __builtin_amdgcn_s_barrier(); \
    asm volatile("s_waitcnt lgkmcnt(0)" ::: "memory"); \
  } while (0)

  STAGE_A(0, 0, 0); STAGE_B(0, 0, 0);
  STAGE_A(1, 0, 0); STAGE_B(1, 0, 0);
  STAGE_A(0, 1, 1); STAGE_B(0, 1, 1);
  PWAIT_V(0);

  bf16x8 af[8], bf0[4], bf1[4];
  for (int kt = 0; kt < 16; kt++) {
    const int cur = kt & 1;
    const int tail = (kt >= 14);
    const u16* A_ = sA[cur];
    const u16* B_ = sB[cur];

    // ---- phase 0 ----
    #pragma unroll
    for (int mi = 0; mi < 4; mi++)
      #pragma unroll
      for (int ks = 0; ks < 2; ks++) {
        int row = wm2 * 128 + mi * 16 + c;
        af[mi * 2 + ks] = *(const bf16x8*)(A_ + row * 64 + (((ks * 4 + g) ^ (row & 7)) * 8));
      }
    #pragma unroll
    for (int ni = 0; ni < 2; ni++)
      #pragma unroll
      for (int ks = 0; ks < 2; ks++) {
        int row = wn4 * 64 + ni * 16 + c;
        bf0[ni * 2 + ks] = *(const bf16x8*)(B_ + row * 64 + (((ks * 4 + g) ^ (row & 7)) * 8));
      }
    if (kt + 1 < 16) STAGE_A(1, kt + 1, (kt + 1) & 1);
    PWAIT_V(tail);
    __builtin_amdgcn_s_setprio(1);
    #pragma unroll
    for (int mi = 0; mi < 4; mi++)
      #pragma unroll
      for (int ni = 0; ni < 2; ni++)
        #pragma unroll
        for (int ks = 0; ks < 2; ks++)
          acc[mi][ni] = __builtin_amdgcn_mfma_f32_16x16x32_bf16(af[mi * 2 + ks], bf0[ni * 2 + ks], acc[mi][ni], 0, 0, 0);
    __builtin_amdgcn_s_setprio(0);

    // ---- phase 1 ----
    #pragma unroll
    for (int ni = 0; ni < 2; ni++)
      #pragma unroll
      for (int ks = 0; ks < 2; ks++) {
        int row = wn4 * 64 + 32 + ni * 16 + c;
        bf1[ni * 2 + ks] = *(const bf16x8*)(B_ + row * 64 + (((ks * 4 + g) ^ (row & 7)) * 8));
      }
    if (kt + 1 < 16) STAGE_B(1, kt + 1, (kt + 1) & 1);
    PWAIT_N();
    __builtin_amdgcn_s_setprio(1);
    #pragma unroll
    for (int mi = 0; mi < 4; mi++)
      #pragma unroll
      for (int ni = 0; ni < 2; ni++)
        #pragma unroll
        for (int ks = 0; ks < 2; ks++)
          acc[mi][2 + ni] = __builtin_amdgcn_mfma_f32_16x16x32_bf16(af[mi * 2 + ks], bf1[ni * 2 + ks], acc[mi][2 + ni], 0, 0, 0);
    __builtin_amdgcn_s_setprio(0);

    // ---- phase 2 ----
    #pragma unroll
    for (int mi = 0; mi < 4; mi++)
      #pragma unroll
      for (int ks = 0; ks < 2; ks++) {
        int row = wm2 * 128 + 64 + mi * 16 + c;
        af[mi * 2 + ks] = *(const bf16x8*)(A_ + row * 64 + (((ks * 4 + g) ^ (row & 7)) * 8));
      }
    if (kt + 2 < 16) STAGE_A(0, kt + 2, cur);
    PWAIT_N();
    __builtin_amdgcn_s_setprio(1);
    #pragma unroll
    for (int mi = 0; mi < 4; mi++)
      #pragma unroll
      for (int ni = 0; ni < 2; ni++)
        #pragma unroll
        for (int ks = 0; ks < 2; ks++)
          acc[4 + mi][ni] = __builtin_amdgcn_mfma_f32_16x16x32_bf16(af[mi * 2 + ks], bf0[ni * 2 + ks], acc[4 + mi][ni], 0, 0, 0);
    __builtin_amdgcn_s_setprio(0);

    // ---- phase 3 ----
    if (kt + 2 < 16) STAGE_B(0, kt + 2, cur);
    PWAIT_N();
    __builtin_amdgcn_s_setprio(1);
    #pragma unroll
    for (int mi = 0; mi < 4; mi++)
      #pragma unroll
      for (int ni = 0; ni < 2; ni++)
        #pragma unroll
        for (int ks = 0; ks < 2; ks++)
          acc[4 + mi][2 + ni] = __builtin_amdgcn_mfma_f32_16x16x32_bf16(af[mi * 2 + ks], bf1[ni * 2 + ks], acc[4 + mi][2 + ni], 0, 0, 0);
    __builtin_amdgcn_s_setprio(0);
  }

  // epilogue: Q,K scatter
  #pragma unroll
  for (int am = 0; am < 8; am++) {
    int grow0 = bm * 256 + wm2 * 128 + (am >> 2) * 64 + (am & 3) * 16 + g * 4;
    int b = grow0 >> 11, s0 = grow0 & 2047;
    #pragma unroll
    for (int an = 0; an < 4; an++) {
      int gcol = bn * 256 + wn4 * 64 + (an >> 1) * 32 + (an & 1) * 16 + c;
      int which = gcol >> 10, rem = gcol & 1023;
      int hh = rem >> 6, dd = rem & 63;
      u16* dh = which ? Kh : Qh;
      float sc = which ? 1.0f : QSCALE;
      #pragma unroll
      for (int r = 0; r < 4; r++) {
        size_t off = ((size_t)(b * 16 + hh) * 2048 + (s0 + r)) * 64 + dd;
        dh[off] = f2bf(acc[am][an][r] * sc);
      }
    }
  }
#undef STAGE_A
#undef STAGE_B
#undef PWAIT_V
#undef PWAIT_N
}

// ---------------- K2b/K4: 128x128 single-buffer GEMM (wave-overlap regime) --
template <int MODE>
__global__ __launch_bounds__(256) void k_gemm2(
    const u16* __restrict__ Ah, const u16* __restrict__ Bh,
    u16* __restrict__ Vth, float* __restrict__ Cout,
    const float* __restrict__ bias) {
  __shared__ u16 sA[128 * 64];
  __shared__ u16 sB[128 * 64];
  const int t = threadIdx.x, lane = t & 63, w = t >> 6;
  const int bm = blockIdx.x, bn = blockIdx.y;
  const int wm = (w >> 1) * 64, wn = (w & 1) * 64;
  const int g = lane >> 4, c = lane & 15;
  const size_t arow0 = (size_t)bm * 128, brow0 = (size_t)bn * 128;

  f32x4 acc[4][4] = {};

  for (int kt = 0; kt < 16; kt++) {
    __syncthreads();
    #pragma unroll
    for (int i = 0; i < 4; i++) {
      int ci = t + i * 256;
      int r = ci >> 3, cc = ci & 7;
      int cs = cc ^ (r & 7);
      size_t ka = (size_t)kt * 64 + cs * 8;
      gl16(Ah + (arow0 + r) * 1024 + ka, sA + (size_t)ci * 8);
      gl16(Bh + (brow0 + r) * 1024 + ka, sB + (size_t)ci * 8);
    }
    __syncthreads();
    #pragma unroll
    for (int ks = 0; ks < 2; ks++) {
      bf16x8 afh[4], bfh[4];
      #pragma unroll
      for (int mi = 0; mi < 4; mi++) {
        int row = wm + mi * 16 + c;
        afh[mi] = *(const bf16x8*)(sA + row * 64 + (((ks * 4 + g) ^ (row & 7)) * 8));
      }
      #pragma unroll
      for (int ni = 0; ni < 4; ni++) {
        int row = wn + ni * 16 + c;
        bfh[ni] = *(const bf16x8*)(sB + row * 64 + (((ks * 4 + g) ^ (row & 7)) * 8));
      }
      #pragma unroll
      for (int mi = 0; mi < 4; mi++)
        #pragma unroll
        for (int ni = 0; ni < 4; ni++)
          acc[mi][ni] = __builtin_amdgcn_mfma_f32_16x16x32_bf16(afh[mi], bfh[ni], acc[mi][ni], 0, 0, 0);
    }
  }

  if (MODE == 2) {                       // V -> transposed [B,H,Dh,S]
    #pragma unroll
    for (int mi = 0; mi < 4; mi++) {
      int grow0 = bm * 128 + wm + mi * 16 + g * 4;
      int b = grow0 >> 11, s0 = grow0 & 2047;
      #pragma unroll
      for (int ni = 0; ni < 4; ni++) {
        int vcol = bn * 128 + wn + ni * 16 + c;
        int hh = vcol >> 6, dd = vcol & 63;
        u16x4 hv;
        #pragma unroll
        for (int r = 0; r < 4; r++) hv[r] = f2bf(acc[mi][ni][r]);
        size_t off = ((size_t)((b * 16 + hh) * 64 + dd)) * 2048 + s0;
        *(u16x4*)(Vth + off) = hv;
      }
    }
  } else {                               // out-proj: +bias, fp32
    #pragma unroll
    for (int mi = 0; mi < 4; mi++) {
      int grow0 = bm * 128 + wm + mi * 16 + g * 4;
      #pragma unroll
      for (int ni = 0; ni < 4; ni++) {
        int gcol = bn * 128 + wn + ni * 16 + c;
        float bb = bias[gcol];
        #pragma unroll
        for (int r = 0; r < 4; r++)
          Cout[(size_t)(grow0 + r) * 1024 + gcol] = acc[mi][ni][r] + bb;
      }
    }
  }
}

// ---------------- K3: block-causal flash attention (v10: paired q-tiles) ----
// grid (64 b*h, 8); block processes q-tiles {15-y, y}: ntiles(qt)=(qt/2+1)*2
// sums to EXACTLY 18 for every pair -> 512 uniform blocks = steady 2/CU (the
// 64KB LDS cap; pairing no longer cuts residency), all CUs finish together.
// Long half first; per-half prologue fenced by prior half's trailing barrier.
__global__ __launch_bounds__(512, 4) void k_attn(
    const u16* __restrict__ Qh, const u16* __restrict__ Kh,
    const u16* __restrict__ Vth, u16* __restrict__ Oh) {
  __shared__ u16 lK[2][128 * 64], lV[2][64 * 128];
  const int t = threadIdx.x, lane = t & 63, w = t >> 6;
  const int bh = blockIdx.x;
  const int b = bh >> 4, h = bh & 15;
  const int g = lane >> 4, c = lane & 15;

  const u16* Kb = Kh + (size_t)bh * 2048 * 64;
  const u16* Vb = Vth + (size_t)bh * 64 * 2048;

  int kbase[2], vbase[4];
  #pragma unroll
  for (int ks = 0; ks < 2; ks++) kbase[ks] = c * 64 + (((ks * 4 + g) ^ (c & 7)) * 8);
  #pragma unroll
  for (int ks = 0; ks < 4; ks++) vbase[ks] = c * 128 + (((ks * 4 + g) ^ c) * 8);

  const int kr0 = t >> 3, kcs0 = (t & 7) ^ (kr0 & 7);
  const int vr0 = t >> 4, vcs0 = (t & 15) ^ (vr0 & 15);

  const bf16x8 vones = {(short)0x3F80, (short)0x3F80, (short)0x3F80, (short)0x3F80,
                        (short)0x3F80, (short)0x3F80, (short)0x3F80, (short)0x3F80};

  for (int half = 0; half < 2; half++) {
    const int qt = half ? blockIdx.y : 15 - blockIdx.y;  // long half first
    const int qrow0 = qt * 128;
    const int kvlen = (qt / 2 + 1) * 256;
    const int ntiles = kvlen >> 7;

    // Q fragments: wave w covers q-rows [qrow0 + w*16, +16)
    bf16x8 qf[2];
    {
      const u16* qb = Qh + ((size_t)bh * 2048 + qrow0 + w * 16) * 64;
      #pragma unroll
      for (int ks = 0; ks < 2; ks++)
        qf[ks] = *(const bf16x8*)(qb + (size_t)c * 64 + ks * 32 + g * 8);
    }

    float mrun = 0.f;
    f32x4 lsum = {0.f, 0.f, 0.f, 0.f};
    f32x4 o[4] = {};

    // prologue: stage tile 0 into buffer 0 (fenced by prior half's barrier)
    gl16(Kb + (size_t)kr0 * 64 + kcs0 * 8, lK[0] + (size_t)t * 8);
    gl16(Kb + (size_t)(kr0 + 64) * 64 + kcs0 * 8, lK[0] + (size_t)(t + 512) * 8);
    gl16(Vb + (size_t)vr0 * 2048 + vcs0 * 8, lV[0] + (size_t)t * 8);
    gl16(Vb + (size_t)(vr0 + 32) * 2048 + vcs0 * 8, lV[0] + (size_t)(t + 512) * 8);
    __syncthreads();

    const u16* gK = Kb + (size_t)(128 + kr0) * 64 + kcs0 * 8;
    const u16* gV = Vb + (size_t)vr0 * 2048 + 128 + vcs0 * 8;

    for (int kt = 0; kt < ntiles; kt++) {
      const int cur = kt & 1, nxt = cur ^ 1;
      if (kt + 1 < ntiles) {
        gl16(gK, lK[nxt] + (size_t)t * 8);
        gl16(gK + 64 * 64, lK[nxt] + (size_t)(t + 512) * 8);
        gl16(gV, lV[nxt] + (size_t)t * 8);
        gl16(gV + 32 * 2048, lV[nxt] + (size_t)(t + 512) * 8);
        gK += 128 * 64;  gV += 128;
      }

      // S^T - mrun = mfma(A=K, B=Q, C=-mrun)
      f32x4 s[8];
      #pragma unroll
      for (int ni = 0; ni < 8; ni++)
        s[ni] = (f32x4){-mrun, -mrun, -mrun, -mrun};
      __builtin_amdgcn_s_setprio(1);
      #pragma unroll
      for (int ni = 0; ni < 8; ni++)
        #pragma unroll
        for (int ks = 0; ks < 2; ks++) {
          bf16x8 kf = *(const bf16x8*)(lK[cur] + ni * 1024 + kbase[ks]);
          s[ni] = __builtin_amdgcn_mfma_f32_16x16x32_bf16(kf, qf[ks], s[ni], 0, 0, 0);
        }
      __builtin_amdgcn_s_setprio(0);

      // defer-max: lane-local partial max of the shifted scores
      float tl = fmaxf(fmaxf(fmaxf(fmax4(s[0]), fmax4(s[1])), fmaxf(fmax4(s[2]), fmax4(s[3]))),
                       fmaxf(fmaxf(fmax4(s[4]), fmax4(s[5])), fmaxf(fmax4(s[6]), fmax4(s[7]))));
      if (!__all(tl <= 8.0f)) {
        float tm = fmaxf(tl, __shfl_xor(tl, 16));
        tm = fmaxf(tm, __shfl_xor(tm, 32));
        float delta = fmaxf(tm, 0.0f);
        mrun += delta;
        float al = fexp2(-delta);
        #pragma unroll
        for (int ni = 0; ni < 8; ni++)
          #pragma unroll
          for (int r = 0; r < 4; r++) s[ni][r] -= delta;
        #pragma unroll
        for (int r = 0; r < 4; r++) {
          float ar = __shfl(al, g * 4 + r);
          lsum[r] *= ar;
          #pragma unroll
          for (int di = 0; di < 4; di++) o[di][r] *= ar;
        }
      }

      // p = exp2(s) -> bf16 pack -> permlane -> PV A-frags
      bf16x8 pa[4];
      #pragma unroll
      for (int ks = 0; ks < 4; ks++) {
        unsigned int e0 = cvtpk(fexp2(s[2 * ks][0]), fexp2(s[2 * ks][1]));
        unsigned int e1 = cvtpk(fexp2(s[2 * ks][2]), fexp2(s[2 * ks][3]));
        unsigned int f0 = cvtpk(fexp2(s[2 * ks + 1][0]), fexp2(s[2 * ks + 1][1]));
        unsigned int f1 = cvtpk(fexp2(s[2 * ks + 1][2]), fexp2(s[2 * ks + 1][3]));
        asm volatile("v_permlane32_swap_b32 %0, %1" : "+v"(e0), "+v"(f0));
        asm volatile("v_permlane16_swap_b32 %0, %1" : "+v"(e0), "+v"(f0));
        asm volatile("v_permlane32_swap_b32 %0, %1" : "+v"(e1), "+v"(f1));
        asm volatile("v_permlane16_swap_b32 %0, %1" : "+v"(e1), "+v"(f1));
        union { u32x4 u; bf16x8 bv; } cvu;
        cvu.u = (u32x4){e0, e1, f0, f1};
        pa[ks] = cvu.bv;
      }

      // PV: O += P * V; row-sum via ones-MFMA
      __builtin_amdgcn_s_setprio(1);
      #pragma unroll
      for (int di = 0; di < 4; di++)
        #pragma unroll
        for (int ks = 0; ks < 4; ks++) {
          bf16x8 vf = *(const bf16x8*)(lV[cur] + di * 2048 + vbase[ks]);
          o[di] = __builtin_amdgcn_mfma_f32_16x16x32_bf16(pa[ks], vf, o[di], 0, 0, 0);
        }
      #pragma unroll
      for (int ks = 0; ks < 4; ks++)
        lsum = __builtin_amdgcn_mfma_f32_16x16x32_bf16(pa[ks], vones, lsum, 0, 0, 0);
      __builtin_amdgcn_s_setprio(0);

      __syncthreads();
    }

    // epilogue: normalize, write attnout bf16
    #pragma unroll
    for (int r = 0; r < 4; r++) {
      float ir = 1.0f / lsum[r];
      int srow = qrow0 + w * 16 + g * 4 + r;
      size_t rowo = ((size_t)b * 2048 + srow) * 1024 + h * 64;
      #pragma unroll
      for (int di = 0; di < 4; di++)
        Oh[rowo + di * 16 + c] = f2bf(o[di][r] * ir);
    }
  }
}

// ---------------- launch ----------------
extern "C" void kernel_launch(void* const* d_in, const int* in_sizes, int n_in,
                              void* d_out, int out_size, void* d_ws, size_t ws_size,
                              hipStream_t stream) {
  const float* x     = (const float*)d_in[0];
  const float* gamma = (const float*)d_in[1];
  const float* beta  = (const float*)d_in[2];
  const float* Wqkv  = (const float*)d_in[3];
  const float* Wout  = (const float*)d_in[4];
  const float* bout  = (const float*)d_in[5];
  float* out = (float*)d_out;

  char* ws = (char*)d_ws;
  size_t off = 0;
  auto alloc = [&](size_t bytes) { char* p = ws + off; off += (bytes + 255) & ~(size_t)255; return p; };
  const size_t SZ_XN = (size_t)8192 * 1024 * 2;
  const size_t SZ_WQ = (size_t)3072 * 1024 * 2;
  const size_t SZ_WO = (size_t)1024 * 1024 * 2;
  const size_t SZ_QKV = (size_t)4 * 16 * 2048 * 64 * 2;
  u16* xnh  = (u16*)alloc(SZ_XN);   // also attnout (bf16) after attention
  u16* wqth = (u16*)alloc(SZ_WQ);
  u16* woth = (u16*)alloc(SZ_WO);
  u16* Qh  = (u16*)alloc(SZ_QKV);
  u16* Kh  = (u16*)alloc(SZ_QKV);
  u16* Vth = (u16*)alloc(SZ_QKV);
  if (off > ws_size) return;

  k_ln_split<<<8192, 256, 0, stream>>>(x, gamma, beta, xnh);
  k_wsplit_t<<<dim3(96, 32), 256, 0, stream>>>(Wqkv, wqth, 1024, 3072);
  k_wsplit_t<<<dim3(32, 32), 256, 0, stream>>>(Wout, woth, 1024, 1024);
  // Q,K projection: 256 blocks = exactly one clean round at 1 block/CU
  k_gemmq<<<dim3(32, 8), 512, 0, stream>>>(xnh, wqth, Qh, Kh);
  // V projection: 512 blocks all-resident at 4 blocks/CU
  k_gemm2<2><<<dim3(64, 8), 256, 0, stream>>>(xnh, wqth + (size_t)2048 * 1024,
                                              Vth, nullptr, nullptr);
  // attnout (bf16) reuses the xn buffer (xn is dead after the QKV GEMMs)
  k_attn<<<dim3(64, 8), 512, 0, stream>>>(Qh, Kh, Vth, xnh);
  k_gemm2<1><<<dim3(64, 8), 256, 0, stream>>>(xnh, woth,
                                              nullptr, out, bout);
}